// Round 13
// baseline (295.043 us; speedup 1.0000x reference)
//
#include <hip/hip_runtime.h>
#include <math.h>

// Transformer block: pre-LN attn + residual, pre-LN MLP(GELU) + residual.
// B=2,S=2048,D=1024,H=16,hd=64,F=4096. fp32 in/out, bf16 MFMA compute.

typedef __attribute__((ext_vector_type(8))) short s8v;    // 8 x bf16 (16B)
typedef __attribute__((ext_vector_type(4))) short s4v;    // 4 x bf16 (8B)
typedef __attribute__((ext_vector_type(4))) float f4v;    // 16x16 MFMA acc
typedef __attribute__((ext_vector_type(16))) float f16v;  // 32x32 MFMA acc

#define M_ROWS 4096
#define DM 1024
#define FF 4096
#define QKV_LD 3072   // fused qkv row stride

__device__ inline short f2bf(float f) {
  unsigned u = __builtin_bit_cast(unsigned, f);
  u += 0x7fff + ((u >> 16) & 1);          // round-to-nearest-even
  return (short)(u >> 16);
}
__device__ inline float bf2f(short s) {
  unsigned u = ((unsigned)(unsigned short)s) << 16;
  return __builtin_bit_cast(float, u);
}

// async global->LDS, 16B per lane. dst wave-uniform base; HW writes
// base + lane*16. src is per-lane.
__device__ inline void gload_lds16(const void* g, void* lds) {
  __builtin_amdgcn_global_load_lds(
      (const __attribute__((address_space(1))) unsigned*)(uintptr_t)g,
      (__attribute__((address_space(3))) unsigned*)(unsigned)(uintptr_t)lds,
      16, 0, 0);
}

// hardware transpose read: lane gathers 4 bf16 (verified rounds 3-12 passing).
__device__ inline s4v ds_tr16(unsigned off) {
  s4v r;
  asm volatile("ds_read_b64_tr_b16 %0, %1" : "=v"(r) : "v"(off));
  return r;
}

__device__ inline s8v cat8(s4v a, s4v b) {
  return __builtin_shufflevector(a, b, 0, 1, 2, 3, 4, 5, 6, 7);
}

// v_cvt_pk_bf16_f32: lo16 = bf16(a), hi16 = bf16(b)  (T12 recipe)
__device__ inline unsigned pkbf(float a, float b) {
  unsigned r;
  asm("v_cvt_pk_bf16_f32 %0, %1, %2" : "=v"(r) : "v"(a), "v"(b));
  return r;
}

// tanh-approx GELU (max err ~3e-3 vs erf-GELU; cheap on VALU)
__device__ inline float gelu_t(float x) {
  float x3 = x * x * x;
  float z = fmaf(x3, 0.044715f, x) * 1.5957691216f;  // 2*0.7978845608
  float e = __expf(z);                               // tanh via sigmoid form
  float th = fmaf(-2.0f, __frcp_rn(e + 1.0f), 1.0f); // 1 - 2/(e^2z+1)
  return 0.5f * x * (1.0f + th);
}

// ---------------- weight transpose+convert: W[K][N] f32 -> Wt[N][K] bf16 ----
__global__ void wt_kernel(const float* __restrict__ W, short* __restrict__ Wt,
                          int K, int N) {
  __shared__ float tile[32][33];
  int tx = threadIdx.x, ty = threadIdx.y;            // (32,8)
  int n0 = blockIdx.x * 32, k0 = blockIdx.y * 32;
#pragma unroll
  for (int i = 0; i < 4; ++i)
    tile[ty + 8 * i][tx] = W[(size_t)(k0 + ty + 8 * i) * N + n0 + tx];
  __syncthreads();
#pragma unroll
  for (int i = 0; i < 4; ++i)
    Wt[(size_t)(n0 + ty + 8 * i) * K + k0 + tx] = f2bf(tile[tx][ty + 8 * i]);
}

// ---------------- LayerNorm: f32 [rows][1024] -> bf16 ----------------------
__global__ __launch_bounds__(256) void ln_kernel(const float* __restrict__ x,
                                                 const float* __restrict__ g,
                                                 const float* __restrict__ b,
                                                 short* __restrict__ out) {
  int row = blockIdx.x, tid = threadIdx.x;
  const float4* xr = (const float4*)(x + (size_t)row * DM);
  float4 v = xr[tid];                                 // 256 threads * 4 = 1024
  float s = v.x + v.y + v.z + v.w;
  float q = v.x * v.x + v.y * v.y + v.z * v.z + v.w * v.w;
#pragma unroll
  for (int off = 32; off; off >>= 1) {
    s += __shfl_down(s, off);
    q += __shfl_down(q, off);
  }
  __shared__ float red[8];
  if ((tid & 63) == 0) { red[tid >> 6] = s; red[4 + (tid >> 6)] = q; }
  __syncthreads();
  if (tid == 0) {
    float S = red[0] + red[1] + red[2] + red[3];
    float Q = red[4] + red[5] + red[6] + red[7];
    float mean = S * (1.0f / DM);
    float var = Q * (1.0f / DM) - mean * mean;
    red[0] = mean;
    red[1] = rsqrtf(var + 1e-5f);
  }
  __syncthreads();
  float mean = red[0], rstd = red[1];
  float4 gv = ((const float4*)g)[tid], bv = ((const float4*)b)[tid];
  s4v o;
  o[0] = f2bf((v.x - mean) * rstd * gv.x + bv.x);
  o[1] = f2bf((v.y - mean) * rstd * gv.y + bv.y);
  o[2] = f2bf((v.z - mean) * rstd * gv.z + bv.z);
  o[3] = f2bf((v.w - mean) * rstd * gv.w + bv.w);
  *(s4v*)&out[(size_t)row * DM + tid * 4] = o;
}

// ---------------- GEMM 128x128 single-buffer (m97 structure) ---------------
// 32KB LDS -> up to 4-5 blocks/CU; staging latency hidden by co-resident
// blocks (TLP), not by explicit prefetch. Use for grids >= 3 blocks/CU.
template <int EPI>
__global__ __launch_bounds__(256) void gemm_sb_kernel(
    const short* __restrict__ A, const short* __restrict__ Bt,
    const float* __restrict__ bias, const float* __restrict__ res,
    void* __restrict__ Cout, int M, int N, int K) {
  __shared__ short As[128 * 64];
  __shared__ short Bs[128 * 64];
  int tid = threadIdx.x, lane = tid & 63, wave = tid >> 6;
  int wr = wave >> 1, wc = wave & 1;
  int l16 = lane & 15, lhi = lane >> 4;
  int row0 = blockIdx.y * 128, col0 = blockIdx.x * 128;
  int lrow = lane >> 3, lcol8 = (lane & 7) * 8;

  const f4v fzero = {0.f, 0.f, 0.f, 0.f};
  f4v acc[4][4];
#pragma unroll
  for (int m = 0; m < 4; ++m)
#pragma unroll
    for (int n = 0; n < 4; ++n) acc[m][n] = fzero;

  for (int k0 = 0; k0 < K; k0 += 64) {
    __syncthreads();
#pragma unroll
    for (int i = 0; i < 4; ++i) {
      int ch = wave * 4 + i;
      int row = ch * 8 + lrow;
      gload_lds16(&A[(size_t)(row0 + row) * K + k0 + lcol8], &As[ch * 512]);
      gload_lds16(&Bt[(size_t)(col0 + row) * K + k0 + lcol8], &Bs[ch * 512]);
    }
    __syncthreads();
#pragma unroll
    for (int kk = 0; kk < 2; ++kk) {
      s8v af[4], bfr[4];
#pragma unroll
      for (int m = 0; m < 4; ++m)
        af[m] = *(const s8v*)&As[(wr * 64 + m * 16 + l16) * 64 + kk * 32 + lhi * 8];
#pragma unroll
      for (int n = 0; n < 4; ++n)
        bfr[n] = *(const s8v*)&Bs[(wc * 64 + n * 16 + l16) * 64 + kk * 32 + lhi * 8];
#pragma unroll
      for (int m = 0; m < 4; ++m)
#pragma unroll
        for (int n = 0; n < 4; ++n)
          acc[m][n] = __builtin_amdgcn_mfma_f32_16x16x32_bf16(af[m], bfr[n],
                                                              acc[m][n], 0, 0, 0);
    }
  }

#pragma unroll
  for (int m = 0; m < 4; ++m)
#pragma unroll
    for (int n = 0; n < 4; ++n)
#pragma unroll
      for (int r = 0; r < 4; ++r) {
        int row = row0 + wr * 64 + m * 16 + lhi * 4 + r;
        int col = col0 + wc * 64 + n * 16 + l16;
        size_t idx = (size_t)row * N + col;
        float v = acc[m][n][r];
        if (EPI == 0) {
          ((short*)Cout)[idx] = f2bf(v);
        } else if (EPI == 1) {
          ((float*)Cout)[idx] = v + bias[col] + res[idx];
        } else {
          ((short*)Cout)[idx] = f2bf(gelu_t(v + bias[col]));
        }
      }
}

// ---------------- GEMM 128x128, 2-phase dbuf (for 1-block/CU grids) --------
template <int EPI>
__global__ __launch_bounds__(256) void gemm_kernel(
    const short* __restrict__ A, const short* __restrict__ Bt,
    const float* __restrict__ bias, const float* __restrict__ res,
    void* __restrict__ Cout, int M, int N, int K) {
  __shared__ short As[2][128 * 64];
  __shared__ short Bs[2][128 * 64];
  int tid = threadIdx.x, lane = tid & 63, wave = tid >> 6;
  int wr = wave >> 1, wc = wave & 1;
  int l16 = lane & 15, lhi = lane >> 4;
  int row0 = blockIdx.y * 128, col0 = blockIdx.x * 128;
  int lrow = lane >> 3, lcol8 = (lane & 7) * 8;     // staging lane coords

  const f4v fzero = {0.f, 0.f, 0.f, 0.f};
  f4v acc[4][4];
#pragma unroll
  for (int m = 0; m < 4; ++m)
#pragma unroll
    for (int n = 0; n < 4; ++n) acc[m][n] = fzero;

  const int nt = K >> 6;

  // prologue: stage tile 0 into buf 0
#pragma unroll
  for (int i = 0; i < 4; ++i) {
    int ch = wave * 4 + i;
    int row = ch * 8 + lrow;
    gload_lds16(&A[(size_t)(row0 + row) * K + lcol8], &As[0][ch * 512]);
    gload_lds16(&Bt[(size_t)(col0 + row) * K + lcol8], &Bs[0][ch * 512]);
  }
  __syncthreads();   // drains vmcnt(0): buf 0 ready

  for (int t = 0; t < nt; ++t) {
    int cur = t & 1, nxt = cur ^ 1;
    if (t + 1 < nt) {
      int k1 = (t + 1) << 6;
#pragma unroll
      for (int i = 0; i < 4; ++i) {
        int ch = wave * 4 + i;
        int row = ch * 8 + lrow;
        gload_lds16(&A[(size_t)(row0 + row) * K + k1 + lcol8], &As[nxt][ch * 512]);
        gload_lds16(&Bt[(size_t)(col0 + row) * K + k1 + lcol8], &Bs[nxt][ch * 512]);
      }
    }
#pragma unroll
    for (int kk = 0; kk < 2; ++kk) {
      s8v af[4], bfr[4];
#pragma unroll
      for (int m = 0; m < 4; ++m)
        af[m] = *(const s8v*)&As[cur][(wr * 64 + m * 16 + l16) * 64 + kk * 32 + lhi * 8];
#pragma unroll
      for (int n = 0; n < 4; ++n)
        bfr[n] = *(const s8v*)&Bs[cur][(wc * 64 + n * 16 + l16) * 64 + kk * 32 + lhi * 8];
#pragma unroll
      for (int m = 0; m < 4; ++m)
#pragma unroll
        for (int n = 0; n < 4; ++n)
          acc[m][n] = __builtin_amdgcn_mfma_f32_16x16x32_bf16(af[m], bfr[n],
                                                              acc[m][n], 0, 0, 0);
    }
    __syncthreads();   // retires prefetch into nxt; releases cur for re-stage
  }

  // epilogue: D layout col=lane&15, row=(lane>>4)*4+reg
#pragma unroll
  for (int m = 0; m < 4; ++m)
#pragma unroll
    for (int n = 0; n < 4; ++n)
#pragma unroll
      for (int r = 0; r < 4; ++r) {
        int row = row0 + wr * 64 + m * 16 + lhi * 4 + r;
        int col = col0 + wc * 64 + n * 16 + l16;
        size_t idx = (size_t)row * N + col;
        float v = acc[m][n][r];
        if (EPI == 0) {
          ((short*)Cout)[idx] = f2bf(v);
        } else if (EPI == 1) {
          ((float*)Cout)[idx] = v + bias[col] + res[idx];
        } else {
          ((short*)Cout)[idx] = f2bf(gelu_t(v + bias[col]));
        }
      }
}

// ---------------- Flash attention, 8-wave blocks, KV-split x2 ---------------
__global__ __launch_bounds__(512) void attn_kernel(const short* __restrict__ q,
                                                   const short* __restrict__ k,
                                                   const short* __restrict__ v,
                                                   short* __restrict__ opart,
                                                   float2* __restrict__ ml) {
  __shared__ short Ks[2][64 * 64];  // [key][d] XOR-swizzled (16B granules)
  __shared__ short Vt[2][64 * 64];  // 4 regions [64 key][16 d] stride-16
  int tid = threadIdx.x, lane = tid & 63, w = tid >> 6;   // w in 0..7
  int l31 = lane & 31, l15 = lane & 15, h = lane >> 5;
  int qb = blockIdx.x * 256;
  int bh = blockIdx.y;
  int sp = blockIdx.z;
  int b = bh >> 4, hh = bh & 15;
  const size_t rbase = (size_t)b * 2048 * QKV_LD + (size_t)hh * 64;
  const float S2 = 0.18033688f;     // 0.125 * log2(e)
  const int kbase = sp * 1024;      // this split's first key

  // staging coords: wave w stages K chunk w (rows w*8..w*8+7) and V chunk w
  int krow = w * 8 + (lane >> 3);
  int kcol = (((lane & 7) ^ (krow & 7)) * 8);
  int vnb = w >> 1, vrem = (w & 1) * 64 + lane;
  int vkey = vrem >> 1, vc8 = vrem & 1;

#define STAGE_KV(buf, kt)                                                      \
  {                                                                            \
    gload_lds16(&k[rbase + (size_t)((kt) + krow) * QKV_LD + kcol],             \
                &Ks[buf][w * 512]);                                            \
    gload_lds16(&v[rbase + (size_t)((kt) + vkey) * QKV_LD + vnb * 16 + vc8 * 8], \
                &Vt[buf][w * 512]);                                            \
  }

  // Q B-fragments: lane holds Q[qrow][16c + 8h .. +8]
  int qrow = qb + w * 32 + l31;
  s8v qf[4];
#pragma unroll
  for (int c = 0; c < 4; ++c)
    qf[c] = *(const s8v*)&q[rbase + (size_t)qrow * QKV_LD + c * 16 + h * 8];

  f16v o0, o1;
#pragma unroll
  for (int i = 0; i < 16; ++i) { o0[i] = 0.f; o1[i] = 0.f; }
  float mreg = -3.0e38f, lsum = 0.f;

  STAGE_KV(0, kbase);
  __syncthreads();   // buf 0 ready

  for (int t = 0; t < 16; ++t) {
    int cur = t & 1;
    if (t + 1 < 16) STAGE_KV(cur ^ 1, kbase + (t + 1) * 64);
    unsigned vtb = (unsigned)(uintptr_t)&Vt[cur][0];

    // ---- T = K @ Q^T (swapped): t0 keys 0..31, t1 keys 32..63
    f16v t0, t1;
#pragma unroll
    for (int i = 0; i < 16; ++i) { t0[i] = 0.f; t1[i] = 0.f; }
    __builtin_amdgcn_s_setprio(1);
#pragma unroll
    for (int c = 0; c < 4; ++c) {
      int slot = ((2 * c + h) ^ (l31 & 7)) * 8;
      s8v k0f = *(const s8v*)&Ks[cur][l31 * 64 + slot];
      s8v k1f = *(const s8v*)&Ks[cur][(32 + l31) * 64 + slot];
      t0 = __builtin_amdgcn_mfma_f32_32x32x16_bf16(k0f, qf[c], t0, 0, 0, 0);
      t1 = __builtin_amdgcn_mfma_f32_32x32x16_bf16(k1f, qf[c], t1, 0, 0, 0);
    }
    __builtin_amdgcn_s_setprio(0);

    // ---- in-register online softmax (raw scores; exp2 with folded scale)
    float mx[8];
#pragma unroll
    for (int i = 0; i < 8; ++i)
      mx[i] = fmaxf(fmaxf(t0[i], t0[i + 8]), fmaxf(t1[i], t1[i + 8]));
    float rm = fmaxf(fmaxf(fmaxf(mx[0], mx[1]), fmaxf(mx[2], mx[3])),
                     fmaxf(fmaxf(mx[4], mx[5]), fmaxf(mx[6], mx[7])));
    rm = fmaxf(rm, __shfl_xor(rm, 32));
    // defer-max (T13): only rescale when some row max grew > 64 raw (8 scaled)
    if (!__all(rm <= mreg + 64.0f)) {
      float newm = fmaxf(mreg, rm);
      float sc = exp2f((mreg - newm) * S2);
      mreg = newm;
#pragma unroll
      for (int i = 0; i < 16; ++i) { o0[i] *= sc; o1[i] *= sc; }
      lsum *= sc;
    }
    float ms2 = mreg * S2;
#pragma unroll
    for (int i = 0; i < 16; ++i) {
      t0[i] = exp2f(fmaf(t0[i], S2, -ms2));
      t1[i] = exp2f(fmaf(t1[i], S2, -ms2));
    }
    float sm[8];
#pragma unroll
    for (int i = 0; i < 8; ++i)
      sm[i] = (t0[i] + t0[i + 8]) + (t1[i] + t1[i + 8]);
    float rs = ((sm[0] + sm[1]) + (sm[2] + sm[3])) +
               ((sm[4] + sm[5]) + (sm[6] + sm[7]));
    rs += __shfl_xor(rs, 32);
    lsum += rs;

    // ---- build PV B-fragments: keys 16c + 8h' + 0..7 per chunk c
    s8v pB[4];
#pragma unroll
    for (int c = 0; c < 4; ++c) {
      int rb = (c & 1) * 8;
      float e0, e1, e2, e3, e4, e5, e6, e7;
      if (c < 2) {
        e0 = t0[rb]; e1 = t0[rb + 1]; e2 = t0[rb + 2]; e3 = t0[rb + 3];
        e4 = t0[rb + 4]; e5 = t0[rb + 5]; e6 = t0[rb + 6]; e7 = t0[rb + 7];
      } else {
        e0 = t1[rb]; e1 = t1[rb + 1]; e2 = t1[rb + 2]; e3 = t1[rb + 3];
        e4 = t1[rb + 4]; e5 = t1[rb + 5]; e6 = t1[rb + 6]; e7 = t1[rb + 7];
      }
      unsigned wA0 = pkbf(e0, e1), wA1 = pkbf(e2, e3);
      unsigned wB0 = pkbf(e4, e5), wB1 = pkbf(e6, e7);
      unsigned s0 = h ? wA0 : wB0, s1 = h ? wA1 : wB1;
      unsigned r0 = __shfl_xor(s0, 32), r1 = __shfl_xor(s1, 32);
      uint4 ww;
      ww.x = h ? r0 : wA0;
      ww.y = h ? r1 : wA1;
      ww.z = h ? wB0 : r0;
      ww.w = h ? wB1 : r1;
      pB[c] = __builtin_bit_cast(s8v, ww);
    }

    // ---- V^T A-fragments via tr reads
    s4v va[2][4][2];
#pragma unroll
    for (int db = 0; db < 2; ++db) {
      unsigned base = vtb + (unsigned)(db * 2 + (l31 >> 4)) * 2048 + 2u * l15;
#pragma unroll
      for (int c = 0; c < 4; ++c) {
        unsigned a = base + (unsigned)(c * 512 + h * 256);  // k0*32 bytes
        va[db][c][0] = ds_tr16(a);
        va[db][c][1] = ds_tr16(a + 128);
      }
    }
    asm volatile("s_waitcnt lgkmcnt(0)");
    __builtin_amdgcn_sched_barrier(0);
    __builtin_amdgcn_s_setprio(1);
#pragma unroll
    for (int c = 0; c < 4; ++c) {
      o0 = __builtin_amdgcn_mfma_f32_32x32x16_bf16(cat8(va[0][c][0], va[0][c][1]),
                                                   pB[c], o0, 0, 0, 0);
      o1 = __builtin_amdgcn_mfma_f32_32x32x16_bf16(cat8(va[1][c][0], va[1][c][1]),
                                                   pB[c], o1, 0, 0, 0);
    }
    __builtin_amdgcn_s_setprio(0);
    __syncthreads();   // retires prefetch; releases cur for next re-stage
  }

  // ---- store UNNORMALIZED partial O (bf16) + (m,l)
  size_t rowg = (size_t)b * 2048 + qrow;
  size_t obase = (size_t)sp * 4096 * 1024 + rowg * 1024 + hh * 64;
#pragma unroll
  for (int db = 0; db < 2; ++db)
#pragma unroll
    for (int qq = 0; qq < 4; ++qq) {
      s4v pv;
#pragma unroll
      for (int i = 0; i < 4; ++i)
        pv[i] = f2bf(db == 0 ? o0[qq * 4 + i] : o1[qq * 4 + i]);
      *(s4v*)&opart[obase + db * 32 + qq * 8 + h * 4] = pv;
    }
  if (h == 0) ml[(size_t)sp * 65536 + rowg * 16 + hh] = make_float2(mreg, lsum);
#undef STAGE_KV
}

// ---------------- combine two KV-split partials -> bf16 attn out -----------
__global__ __launch_bounds__(256) void attn_combine(const short* __restrict__ op,
                                                    const float2* __restrict__ ml,
                                                    short* __restrict__ o) {
  int row = blockIdx.x, t = threadIdx.x;      // 4 outputs per thread
  int head = t >> 4;
  const float S2 = 0.18033688f;
  float2 ml0 = ml[(size_t)row * 16 + head];
  float2 ml1 = ml[65536 + (size_t)row * 16 + head];
  float M = fmaxf(ml0.x, ml1.x);
  float a0 = exp2f((ml0.x - M) * S2);
  float a1 = exp2f((ml1.x - M) * S2);
  float inv = 1.0f / fmaf(ml0.y, a0, ml1.y * a1);
  a0 *= inv; a1 *= inv;
  s4v v0 = *(const s4v*)&op[(size_t)row * 1024 + t * 4];
  s4v v1 = *(const s4v*)&op[(size_t)4096 * 1024 + row * 1024 + t * 4];
  s4v pv;
#pragma unroll
  for (int i = 0; i < 4; ++i)
    pv[i] = f2bf(bf2f(v0[i]) * a0 + bf2f(v1[i]) * a1);
  *(s4v*)&o[(size_t)row * 1024 + t * 4] = pv;
}

// ---------------------------------------------------------------------------
extern "C" void kernel_launch(void* const* d_in, const int* in_sizes, int n_in,
                              void* d_out, int out_size, void* d_ws, size_t ws_size,
                              hipStream_t stream) {
  (void)in_sizes; (void)n_in; (void)out_size; (void)ws_size;
  const float* x    = (const float*)d_in[0];
  const float* ln1g = (const float*)d_in[1];
  const float* ln1b = (const float*)d_in[2];
  const float* wq   = (const float*)d_in[3];
  const float* wk   = (const float*)d_in[4];
  const float* wv   = (const float*)d_in[5];
  const float* wo   = (const float*)d_in[6];
  const float* bo   = (const float*)d_in[7];
  const float* ln2g = (const float*)d_in[8];
  const float* ln2b = (const float*)d_in[9];
  const float* w1   = (const float*)d_in[10];
  const float* b1   = (const float*)d_in[11];
  const float* w2   = (const float*)d_in[12];
  const float* b2   = (const float*)d_in[13];
  float* out = (float*)d_out;

  char* ws = (char*)d_ws;
  const size_t MB = 1024 * 1024;
  short* h1   = (short*)(ws);                 // 8MB  [4096][1024]
  short* qkv  = (short*)(ws + 8 * MB);        // 24MB [4096][3072]
  short* mid  = (short*)(ws);                 // 32MB [4096][4096] (after attn)
  short* at   = (short*)(ws + 32 * MB);       // 8MB  [4096][1024]
  short* h2   = (short*)(ws + 32 * MB);       // reuses at after proj
  float* x2   = (float*)(ws + 40 * MB);       // 16MB f32 residual (after attn)
  short* opart = (short*)(ws + 40 * MB);      // 16MB [2][4096][1024] bf16 partial
  float2* mlb  = (float2*)(ws);               // 1MB  [2][4096][16] (h1 dead)
  short* wqkvT = (short*)(ws + 56 * MB);      // 6MB  [3072][1024]
  short* wqT  = wqkvT;
  short* wkT  = wqkvT + 1024 * 1024;
  short* wvT  = wqkvT + 2 * 1024 * 1024;
  short* woT  = (short*)(ws + 62 * MB);       // 2MB
  short* w1T  = (short*)(ws + 64 * MB);       // 8MB  [4096][1024]
  short* w2T  = (short*)(ws + 72 * MB);       // 8MB  [1024][4096]

  dim3 tb(32, 8);
  wt_kernel<<<dim3(32, 32), tb, 0, stream>>>(wq, wqT, 1024, 1024);
  wt_kernel<<<dim3(32, 32), tb, 0, stream>>>(wk, wkT, 1024, 1024);
  wt_kernel<<<dim3(32, 32), tb, 0, stream>>>(wv, wvT, 1024, 1024);
  wt_kernel<<<dim3(32, 32), tb, 0, stream>>>(wo, woT, 1024, 1024);
  wt_kernel<<<dim3(128, 32), tb, 0, stream>>>(w1, w1T, 1024, 4096);
  wt_kernel<<<dim3(32, 128), tb, 0, stream>>>(w2, w2T, 4096, 1024);

  ln_kernel<<<M_ROWS, 256, 0, stream>>>(x, ln1g, ln1b, h1);

  // fused QKV: [4096][3072], 768 blocks = 3/CU -> single-buffer + TLP
  gemm_sb_kernel<0><<<dim3(24, 32), 256, 0, stream>>>(h1, wqkvT, nullptr, nullptr,
                                                      qkv, M_ROWS, QKV_LD, DM);

  attn_kernel<<<dim3(8, 32, 2), 512, 0, stream>>>(qkv, qkv + 1024, qkv + 2048,
                                                  opart, mlb);
  attn_combine<<<4096, 256, 0, stream>>>(opart, mlb, at);

  // proj: 256 blocks = 1/CU -> dbuf prefetch
  gemm_kernel<1><<<dim3(8, 32), 256, 0, stream>>>(at, woT, bo, x, x2, M_ROWS, DM, DM);

  ln_kernel<<<M_ROWS, 256, 0, stream>>>(x2, ln2g, ln2b, h2);

  // MLP1: 1024 blocks = 4/CU -> single-buffer + TLP
  gemm_sb_kernel<2><<<dim3(32, 32), 256, 0, stream>>>(h2, w1T, b1, nullptr, mid,
                                                      M_ROWS, FF, DM);

  // MLP2: 256 blocks = 1/CU -> dbuf prefetch
  gemm_kernel<1><<<dim3(8, 32), 256, 0, stream>>>(mid, w2T, b2, x2, out,
                                                  M_ROWS, DM, FF);
}

// Round 14
// 294.879 us; speedup vs baseline: 1.0006x; 1.0006x over previous
//
#include <hip/hip_runtime.h>
#include <math.h>

// Transformer block: pre-LN attn + residual, pre-LN MLP(GELU) + residual.
// B=2,S=2048,D=1024,H=16,hd=64,F=4096. fp32 in/out, bf16 MFMA compute.

typedef __attribute__((ext_vector_type(8))) short s8v;    // 8 x bf16 (16B)
typedef __attribute__((ext_vector_type(4))) short s4v;    // 4 x bf16 (8B)
typedef __attribute__((ext_vector_type(4))) float f4v;    // 16x16 MFMA acc
typedef __attribute__((ext_vector_type(16))) float f16v;  // 32x32 MFMA acc

#define M_ROWS 4096
#define DM 1024
#define FF 4096
#define QKV_LD 3072   // fused qkv row stride

__device__ inline short f2bf(float f) {
  unsigned u = __builtin_bit_cast(unsigned, f);
  u += 0x7fff + ((u >> 16) & 1);          // round-to-nearest-even
  return (short)(u >> 16);
}
__device__ inline float bf2f(short s) {
  unsigned u = ((unsigned)(unsigned short)s) << 16;
  return __builtin_bit_cast(float, u);
}

// async global->LDS, 16B per lane. dst wave-uniform base; HW writes
// base + lane*16. src is per-lane.
__device__ inline void gload_lds16(const void* g, void* lds) {
  __builtin_amdgcn_global_load_lds(
      (const __attribute__((address_space(1))) unsigned*)(uintptr_t)g,
      (__attribute__((address_space(3))) unsigned*)(unsigned)(uintptr_t)lds,
      16, 0, 0);
}

// hardware transpose read: lane gathers 4 bf16 (verified rounds 3-13 passing).
__device__ inline s4v ds_tr16(unsigned off) {
  s4v r;
  asm volatile("ds_read_b64_tr_b16 %0, %1" : "=v"(r) : "v"(off));
  return r;
}

__device__ inline s8v cat8(s4v a, s4v b) {
  return __builtin_shufflevector(a, b, 0, 1, 2, 3, 4, 5, 6, 7);
}

// v_cvt_pk_bf16_f32: lo16 = bf16(a), hi16 = bf16(b)  (T12 recipe)
__device__ inline unsigned pkbf(float a, float b) {
  unsigned r;
  asm("v_cvt_pk_bf16_f32 %0, %1, %2" : "=v"(r) : "v"(a), "v"(b));
  return r;
}

// tanh-approx GELU in sigmoid/exp2 form: x * sigmoid(2*0.79788*(x+0.044715x^3))
// == 0.5x(1+tanh(...)). Ops: 3 mul + 1 fma + 1 add + exp2 + rcp.
__device__ inline float gelu_s(float x) {
  float t = x * x;
  float z = fmaf(t, -0.10296333f, -2.88539008f);  // -(2*0.79788*log2e)*(1+0.044715 t)
  float e = exp2f(x * z);                         // exp(-2y)
  return x * __frcp_rn(1.0f + e);
}

// ---------------- weight transpose+convert: W[K][N] f32 -> Wt[N][K] bf16 ----
__global__ void wt_kernel(const float* __restrict__ W, short* __restrict__ Wt,
                          int K, int N) {
  __shared__ float tile[32][33];
  int tx = threadIdx.x, ty = threadIdx.y;            // (32,8)
  int n0 = blockIdx.x * 32, k0 = blockIdx.y * 32;
#pragma unroll
  for (int i = 0; i < 4; ++i)
    tile[ty + 8 * i][tx] = W[(size_t)(k0 + ty + 8 * i) * N + n0 + tx];
  __syncthreads();
#pragma unroll
  for (int i = 0; i < 4; ++i)
    Wt[(size_t)(n0 + ty + 8 * i) * K + k0 + tx] = f2bf(tile[tx][ty + 8 * i]);
}

// fused 4x 1024x1024 transpose (one launch instead of four)
__global__ void wt4_kernel(const float* __restrict__ w0, const float* __restrict__ w1,
                           const float* __restrict__ w2, const float* __restrict__ w3,
                           short* __restrict__ o0, short* __restrict__ o1,
                           short* __restrict__ o2, short* __restrict__ o3) {
  __shared__ float tile[32][33];
  int tx = threadIdx.x, ty = threadIdx.y;
  int n0 = blockIdx.x * 32, k0 = blockIdx.y * 32;
  int zz = blockIdx.z;
  const float* W = zz == 0 ? w0 : zz == 1 ? w1 : zz == 2 ? w2 : w3;
  short* Wt = zz == 0 ? o0 : zz == 1 ? o1 : zz == 2 ? o2 : o3;
#pragma unroll
  for (int i = 0; i < 4; ++i)
    tile[ty + 8 * i][tx] = W[(size_t)(k0 + ty + 8 * i) * 1024 + n0 + tx];
  __syncthreads();
#pragma unroll
  for (int i = 0; i < 4; ++i)
    Wt[(size_t)(n0 + ty + 8 * i) * 1024 + k0 + tx] = f2bf(tile[tx][ty + 8 * i]);
}

// ---------------- LayerNorm: f32 [rows][1024] -> bf16 ----------------------
__global__ __launch_bounds__(256) void ln_kernel(const float* __restrict__ x,
                                                 const float* __restrict__ g,
                                                 const float* __restrict__ b,
                                                 short* __restrict__ out) {
  int row = blockIdx.x, tid = threadIdx.x;
  const float4* xr = (const float4*)(x + (size_t)row * DM);
  float4 v = xr[tid];                                 // 256 threads * 4 = 1024
  float s = v.x + v.y + v.z + v.w;
  float q = v.x * v.x + v.y * v.y + v.z * v.z + v.w * v.w;
#pragma unroll
  for (int off = 32; off; off >>= 1) {
    s += __shfl_down(s, off);
    q += __shfl_down(q, off);
  }
  __shared__ float red[8];
  if ((tid & 63) == 0) { red[tid >> 6] = s; red[4 + (tid >> 6)] = q; }
  __syncthreads();
  if (tid == 0) {
    float S = red[0] + red[1] + red[2] + red[3];
    float Q = red[4] + red[5] + red[6] + red[7];
    float mean = S * (1.0f / DM);
    float var = Q * (1.0f / DM) - mean * mean;
    red[0] = mean;
    red[1] = rsqrtf(var + 1e-5f);
  }
  __syncthreads();
  float mean = red[0], rstd = red[1];
  float4 gv = ((const float4*)g)[tid], bv = ((const float4*)b)[tid];
  s4v o;
  o[0] = f2bf((v.x - mean) * rstd * gv.x + bv.x);
  o[1] = f2bf((v.y - mean) * rstd * gv.y + bv.y);
  o[2] = f2bf((v.z - mean) * rstd * gv.z + bv.z);
  o[3] = f2bf((v.w - mean) * rstd * gv.w + bv.w);
  *(s4v*)&out[(size_t)row * DM + tid * 4] = o;
}

// ---------------- GEMM 128x128, 2-phase dbuf + LDS-staged vector epilogue --
// EPI 0: C bf16 = acc
// EPI 1: C f32  = acc + bias[n] + res[m,n]
// EPI 2: C bf16 = gelu(acc + bias[n])
template <int EPI>
__global__ __launch_bounds__(256) void gemm_kernel(
    const short* __restrict__ A, const short* __restrict__ Bt,
    const float* __restrict__ bias, const float* __restrict__ res,
    void* __restrict__ Cout, int M, int N, int K) {
  __shared__ short As[2][128 * 64];
  __shared__ short Bs[2][128 * 64];
  int tid = threadIdx.x, lane = tid & 63, wave = tid >> 6;
  int wr = wave >> 1, wc = wave & 1;
  int l16 = lane & 15, lhi = lane >> 4;
  int row0 = blockIdx.y * 128, col0 = blockIdx.x * 128;
  int lrow = lane >> 3, lcol8 = (lane & 7) * 8;     // staging lane coords

  const f4v fzero = {0.f, 0.f, 0.f, 0.f};
  f4v acc[4][4];
#pragma unroll
  for (int m = 0; m < 4; ++m)
#pragma unroll
    for (int n = 0; n < 4; ++n) acc[m][n] = fzero;

  const int nt = K >> 6;

  // prologue: stage tile 0 into buf 0
#pragma unroll
  for (int i = 0; i < 4; ++i) {
    int ch = wave * 4 + i;
    int row = ch * 8 + lrow;
    gload_lds16(&A[(size_t)(row0 + row) * K + lcol8], &As[0][ch * 512]);
    gload_lds16(&Bt[(size_t)(col0 + row) * K + lcol8], &Bs[0][ch * 512]);
  }
  __syncthreads();   // drains vmcnt(0): buf 0 ready

  for (int t = 0; t < nt; ++t) {
    int cur = t & 1, nxt = cur ^ 1;
    if (t + 1 < nt) {
      int k1 = (t + 1) << 6;
#pragma unroll
      for (int i = 0; i < 4; ++i) {
        int ch = wave * 4 + i;
        int row = ch * 8 + lrow;
        gload_lds16(&A[(size_t)(row0 + row) * K + k1 + lcol8], &As[nxt][ch * 512]);
        gload_lds16(&Bt[(size_t)(col0 + row) * K + k1 + lcol8], &Bs[nxt][ch * 512]);
      }
    }
#pragma unroll
    for (int kk = 0; kk < 2; ++kk) {
      s8v af[4], bfr[4];
#pragma unroll
      for (int m = 0; m < 4; ++m)
        af[m] = *(const s8v*)&As[cur][(wr * 64 + m * 16 + l16) * 64 + kk * 32 + lhi * 8];
#pragma unroll
      for (int n = 0; n < 4; ++n)
        bfr[n] = *(const s8v*)&Bs[cur][(wc * 64 + n * 16 + l16) * 64 + kk * 32 + lhi * 8];
#pragma unroll
      for (int m = 0; m < 4; ++m)
#pragma unroll
        for (int n = 0; n < 4; ++n)
          acc[m][n] = __builtin_amdgcn_mfma_f32_16x16x32_bf16(af[m], bfr[n],
                                                              acc[m][n], 0, 0, 0);
    }
    __syncthreads();   // retires prefetch into nxt; releases cur for re-stage
  }

  // ---- LDS-staged vectorized epilogue (two 64-row halves through As) ----
  float* Cl = (float*)&As[0][0];            // 64x128 f32 = 32KB
  const float4* Cl4 = (const float4*)Cl;
  int r2 = tid >> 2, cs = (tid & 3) * 32;   // row 0..63, col segment
#pragma unroll
  for (int hf = 0; hf < 2; ++hf) {
    if (wr == hf) {
#pragma unroll
      for (int m = 0; m < 4; ++m)
#pragma unroll
        for (int n = 0; n < 4; ++n)
#pragma unroll
          for (int r = 0; r < 4; ++r)
            Cl[(m * 16 + lhi * 4 + r) * 128 + wc * 64 + n * 16 + l16] = acc[m][n][r];
    }
    __syncthreads();
    int grow = row0 + hf * 64 + r2;
    if (EPI == 1) {
#pragma unroll
      for (int j = 0; j < 8; ++j) {
        float4 v = Cl4[r2 * 32 + (cs >> 2) + j];
        float4 bb = ((const float4*)bias)[(col0 + cs) / 4 + j];
        float4 rr = ((const float4*)res)[((size_t)grow * N + col0 + cs) / 4 + j];
        float4 o;
        o.x = v.x + bb.x + rr.x; o.y = v.y + bb.y + rr.y;
        o.z = v.z + bb.z + rr.z; o.w = v.w + bb.w + rr.w;
        ((float4*)Cout)[((size_t)grow * N + col0 + cs) / 4 + j] = o;
      }
    } else {
#pragma unroll
      for (int j2 = 0; j2 < 4; ++j2) {
        float4 a = Cl4[r2 * 32 + (cs >> 2) + 2 * j2];
        float4 b = Cl4[r2 * 32 + (cs >> 2) + 2 * j2 + 1];
        float e[8] = {a.x, a.y, a.z, a.w, b.x, b.y, b.z, b.w};
        s8v o;
        if (EPI == 2) {
          float4 b0 = ((const float4*)bias)[(col0 + cs) / 4 + 2 * j2];
          float4 b1 = ((const float4*)bias)[(col0 + cs) / 4 + 2 * j2 + 1];
          float bb[8] = {b0.x, b0.y, b0.z, b0.w, b1.x, b1.y, b1.z, b1.w};
#pragma unroll
          for (int i = 0; i < 8; ++i) o[i] = f2bf(gelu_s(e[i] + bb[i]));
        } else {
#pragma unroll
          for (int i = 0; i < 8; ++i) o[i] = f2bf(e[i]);
        }
        *(s8v*)&((short*)Cout)[(size_t)grow * N + col0 + cs + j2 * 8] = o;
      }
    }
    __syncthreads();
  }
}

// ---------------- Flash attention, 8-wave blocks, KV-split x2 ---------------
__global__ __launch_bounds__(512) void attn_kernel(const short* __restrict__ q,
                                                   const short* __restrict__ k,
                                                   const short* __restrict__ v,
                                                   short* __restrict__ opart,
                                                   float2* __restrict__ ml) {
  __shared__ short Ks[2][64 * 64];  // [key][d] XOR-swizzled (16B granules)
  __shared__ short Vt[2][64 * 64];  // 4 regions [64 key][16 d] stride-16
  int tid = threadIdx.x, lane = tid & 63, w = tid >> 6;   // w in 0..7
  int l31 = lane & 31, l15 = lane & 15, h = lane >> 5;
  int qb = blockIdx.x * 256;
  int bh = blockIdx.y;
  int sp = blockIdx.z;
  int b = bh >> 4, hh = bh & 15;
  const size_t rbase = (size_t)b * 2048 * QKV_LD + (size_t)hh * 64;
  const float S2 = 0.18033688f;     // 0.125 * log2(e)
  const int kbase = sp * 1024;      // this split's first key

  // staging coords: wave w stages K chunk w (rows w*8..w*8+7) and V chunk w
  int krow = w * 8 + (lane >> 3);
  int kcol = (((lane & 7) ^ (krow & 7)) * 8);
  int vnb = w >> 1, vrem = (w & 1) * 64 + lane;
  int vkey = vrem >> 1, vc8 = vrem & 1;

#define STAGE_KV(buf, kt)                                                      \
  {                                                                            \
    gload_lds16(&k[rbase + (size_t)((kt) + krow) * QKV_LD + kcol],             \
                &Ks[buf][w * 512]);                                            \
    gload_lds16(&v[rbase + (size_t)((kt) + vkey) * QKV_LD + vnb * 16 + vc8 * 8], \
                &Vt[buf][w * 512]);                                            \
  }

  // Q B-fragments: lane holds Q[qrow][16c + 8h .. +8]
  int qrow = qb + w * 32 + l31;
  s8v qf[4];
#pragma unroll
  for (int c = 0; c < 4; ++c)
    qf[c] = *(const s8v*)&q[rbase + (size_t)qrow * QKV_LD + c * 16 + h * 8];

  f16v o0, o1;
#pragma unroll
  for (int i = 0; i < 16; ++i) { o0[i] = 0.f; o1[i] = 0.f; }
  float mreg = -3.0e38f, lsum = 0.f;

  STAGE_KV(0, kbase);
  __syncthreads();   // buf 0 ready

  for (int t = 0; t < 16; ++t) {
    int cur = t & 1;
    if (t + 1 < 16) STAGE_KV(cur ^ 1, kbase + (t + 1) * 64);
    unsigned vtb = (unsigned)(uintptr_t)&Vt[cur][0];

    // ---- T = K @ Q^T (swapped): t0 keys 0..31, t1 keys 32..63
    f16v t0, t1;
#pragma unroll
    for (int i = 0; i < 16; ++i) { t0[i] = 0.f; t1[i] = 0.f; }
    __builtin_amdgcn_s_setprio(1);
#pragma unroll
    for (int c = 0; c < 4; ++c) {
      int slot = ((2 * c + h) ^ (l31 & 7)) * 8;
      s8v k0f = *(const s8v*)&Ks[cur][l31 * 64 + slot];
      s8v k1f = *(const s8v*)&Ks[cur][(32 + l31) * 64 + slot];
      t0 = __builtin_amdgcn_mfma_f32_32x32x16_bf16(k0f, qf[c], t0, 0, 0, 0);
      t1 = __builtin_amdgcn_mfma_f32_32x32x16_bf16(k1f, qf[c], t1, 0, 0, 0);
    }
    __builtin_amdgcn_s_setprio(0);

    // ---- in-register online softmax (raw scores; exp2 with folded scale)
    float mx[8];
#pragma unroll
    for (int i = 0; i < 8; ++i)
      mx[i] = fmaxf(fmaxf(t0[i], t0[i + 8]), fmaxf(t1[i], t1[i + 8]));
    float rm = fmaxf(fmaxf(fmaxf(mx[0], mx[1]), fmaxf(mx[2], mx[3])),
                     fmaxf(fmaxf(mx[4], mx[5]), fmaxf(mx[6], mx[7])));
    rm = fmaxf(rm, __shfl_xor(rm, 32));
    // defer-max (T13): only rescale when some row max grew > 64 raw (8 scaled)
    if (!__all(rm <= mreg + 64.0f)) {
      float newm = fmaxf(mreg, rm);
      float sc = exp2f((mreg - newm) * S2);
      mreg = newm;
#pragma unroll
      for (int i = 0; i < 16; ++i) { o0[i] *= sc; o1[i] *= sc; }
      lsum *= sc;
    }
    float ms2 = mreg * S2;
#pragma unroll
    for (int i = 0; i < 16; ++i) {
      t0[i] = exp2f(fmaf(t0[i], S2, -ms2));
      t1[i] = exp2f(fmaf(t1[i], S2, -ms2));
    }
    float sm[8];
#pragma unroll
    for (int i = 0; i < 8; ++i)
      sm[i] = (t0[i] + t0[i + 8]) + (t1[i] + t1[i + 8]);
    float rs = ((sm[0] + sm[1]) + (sm[2] + sm[3])) +
               ((sm[4] + sm[5]) + (sm[6] + sm[7]));
    rs += __shfl_xor(rs, 32);
    lsum += rs;

    // ---- build PV B-fragments: keys 16c + 8h' + 0..7 per chunk c
    s8v pB[4];
#pragma unroll
    for (int c = 0; c < 4; ++c) {
      int rb = (c & 1) * 8;
      float e0, e1, e2, e3, e4, e5, e6, e7;
      if (c < 2) {
        e0 = t0[rb]; e1 = t0[rb + 1]; e2 = t0[rb + 2]; e3 = t0[rb + 3];
        e4 = t0[rb + 4]; e5 = t0[rb + 5]; e6 = t0[rb + 6]; e7 = t0[rb + 7];
      } else {
        e0 = t1[rb]; e1 = t1[rb + 1]; e2 = t1[rb + 2]; e3 = t1[rb + 3];
        e4 = t1[rb + 4]; e5 = t1[rb + 5]; e6 = t1[rb + 6]; e7 = t1[rb + 7];
      }
      unsigned wA0 = pkbf(e0, e1), wA1 = pkbf(e2, e3);
      unsigned wB0 = pkbf(e4, e5), wB1 = pkbf(e6, e7);
      unsigned s0 = h ? wA0 : wB0, s1 = h ? wA1 : wB1;
      unsigned r0 = __shfl_xor(s0, 32), r1 = __shfl_xor(s1, 32);
      uint4 ww;
      ww.x = h ? r0 : wA0;
      ww.y = h ? r1 : wA1;
      ww.z = h ? wB0 : r0;
      ww.w = h ? wB1 : r1;
      pB[c] = __builtin_bit_cast(s8v, ww);
    }

    // ---- V^T A-fragments via tr reads
    s4v va[2][4][2];
#pragma unroll
    for (int db = 0; db < 2; ++db) {
      unsigned base = vtb + (unsigned)(db * 2 + (l31 >> 4)) * 2048 + 2u * l15;
#pragma unroll
      for (int c = 0; c < 4; ++c) {
        unsigned a = base + (unsigned)(c * 512 + h * 256);  // k0*32 bytes
        va[db][c][0] = ds_tr16(a);
        va[db][c][1] = ds_tr16(a + 128);
      }
    }
    asm volatile("s_waitcnt lgkmcnt(0)");
    __builtin_amdgcn_sched_barrier(0);
    __builtin_amdgcn_s_setprio(1);
#pragma unroll
    for (int c = 0; c < 4; ++c) {
      o0 = __builtin_amdgcn_mfma_f32_32x32x16_bf16(cat8(va[0][c][0], va[0][c][1]),
                                                   pB[c], o0, 0, 0, 0);
      o1 = __builtin_amdgcn_mfma_f32_32x32x16_bf16(cat8(va[1][c][0], va[1][c][1]),
                                                   pB[c], o1, 0, 0, 0);
    }
    __builtin_amdgcn_s_setprio(0);
    __syncthreads();   // retires prefetch; releases cur for next re-stage
  }

  // ---- store UNNORMALIZED partial O (bf16) + (m,l)
  size_t rowg = (size_t)b * 2048 + qrow;
  size_t obase = (size_t)sp * 4096 * 1024 + rowg * 1024 + hh * 64;
#pragma unroll
  for (int db = 0; db < 2; ++db)
#pragma unroll
    for (int qq = 0; qq < 4; ++qq) {
      s4v pv;
#pragma unroll
      for (int i = 0; i < 4; ++i)
        pv[i] = f2bf(db == 0 ? o0[qq * 4 + i] : o1[qq * 4 + i]);
      *(s4v*)&opart[obase + db * 32 + qq * 8 + h * 4] = pv;
    }
  if (h == 0) ml[(size_t)sp * 65536 + rowg * 16 + hh] = make_float2(mreg, lsum);
#undef STAGE_KV
}

// ---------------- combine two KV-split partials -> bf16 attn out -----------
__global__ __launch_bounds__(256) void attn_combine(const short* __restrict__ op,
                                                    const float2* __restrict__ ml,
                                                    short* __restrict__ o) {
  int row = blockIdx.x, t = threadIdx.x;      // 4 outputs per thread
  int head = t >> 4;
  const float S2 = 0.18033688f;
  float2 ml0 = ml[(size_t)row * 16 + head];
  float2 ml1 = ml[65536 + (size_t)row * 16 + head];
  float M = fmaxf(ml0.x, ml1.x);
  float a0 = exp2f((ml0.x - M) * S2);
  float a1 = exp2f((ml1.x - M) * S2);
  float inv = 1.0f / fmaf(ml0.y, a0, ml1.y * a1);
  a0 *= inv; a1 *= inv;
  s4v v0 = *(const s4v*)&op[(size_t)row * 1024 + t * 4];
  s4v v1 = *(const s4v*)&op[(size_t)4096 * 1024 + row * 1024 + t * 4];
  s4v pv;
#pragma unroll
  for (int i = 0; i < 4; ++i)
    pv[i] = f2bf(bf2f(v0[i]) * a0 + bf2f(v1[i]) * a1);
  *(s4v*)&o[(size_t)row * 1024 + t * 4] = pv;
}

// ---------------------------------------------------------------------------
extern "C" void kernel_launch(void* const* d_in, const int* in_sizes, int n_in,
                              void* d_out, int out_size, void* d_ws, size_t ws_size,
                              hipStream_t stream) {
  (void)in_sizes; (void)n_in; (void)out_size; (void)ws_size;
  const float* x    = (const float*)d_in[0];
  const float* ln1g = (const float*)d_in[1];
  const float* ln1b = (const float*)d_in[2];
  const float* wq   = (const float*)d_in[3];
  const float* wk   = (const float*)d_in[4];
  const float* wv   = (const float*)d_in[5];
  const float* wo   = (const float*)d_in[6];
  const float* bo   = (const float*)d_in[7];
  const float* ln2g = (const float*)d_in[8];
  const float* ln2b = (const float*)d_in[9];
  const float* w1   = (const float*)d_in[10];
  const float* b1   = (const float*)d_in[11];
  const float* w2   = (const float*)d_in[12];
  const float* b2   = (const float*)d_in[13];
  float* out = (float*)d_out;

  char* ws = (char*)d_ws;
  const size_t MB = 1024 * 1024;
  short* h1   = (short*)(ws);                 // 8MB  [4096][1024]
  short* qkv  = (short*)(ws + 8 * MB);        // 24MB [4096][3072]
  short* mid  = (short*)(ws);                 // 32MB [4096][4096] (after attn)
  short* at   = (short*)(ws + 32 * MB);       // 8MB  [4096][1024]
  short* h2   = (short*)(ws + 32 * MB);       // reuses at after proj
  float* x2   = (float*)(ws + 40 * MB);       // 16MB f32 residual (after attn)
  short* opart = (short*)(ws + 40 * MB);      // 16MB [2][4096][1024] bf16 partial
  float2* mlb  = (float2*)(ws);               // 1MB  [2][4096][16] (h1 dead)
  short* wqkvT = (short*)(ws + 56 * MB);      // 6MB  [3072][1024]
  short* wqT  = wqkvT;
  short* wkT  = wqkvT + 1024 * 1024;
  short* wvT  = wqkvT + 2 * 1024 * 1024;
  short* woT  = (short*)(ws + 62 * MB);       // 2MB
  short* w1T  = (short*)(ws + 64 * MB);       // 8MB  [4096][1024]
  short* w2T  = (short*)(ws + 72 * MB);       // 8MB  [1024][4096]

  dim3 tb(32, 8);
  wt4_kernel<<<dim3(32, 32, 4), tb, 0, stream>>>(wq, wk, wv, wo,
                                                 wqT, wkT, wvT, woT);
  wt_kernel<<<dim3(128, 32), tb, 0, stream>>>(w1, w1T, 1024, 4096);
  wt_kernel<<<dim3(32, 128), tb, 0, stream>>>(w2, w2T, 4096, 1024);

  ln_kernel<<<M_ROWS, 256, 0, stream>>>(x, ln1g, ln1b, h1);

  // fused QKV: [4096][3072]
  gemm_kernel<0><<<dim3(24, 32), 256, 0, stream>>>(h1, wqkvT, nullptr, nullptr,
                                                   qkv, M_ROWS, QKV_LD, DM);

  attn_kernel<<<dim3(8, 32, 2), 512, 0, stream>>>(qkv, qkv + 1024, qkv + 2048,
                                                  opart, mlb);
  attn_combine<<<4096, 256, 0, stream>>>(opart, mlb, at);

  gemm_kernel<1><<<dim3(8, 32), 256, 0, stream>>>(at, woT, bo, x, x2, M_ROWS, DM, DM);

  ln_kernel<<<M_ROWS, 256, 0, stream>>>(x2, ln2g, ln2b, h2);

  gemm_kernel<2><<<dim3(32, 32), 256, 0, stream>>>(h2, w1T, b1, nullptr, mid,
                                                   M_ROWS, FF, DM);

  gemm_kernel<1><<<dim3(8, 32), 256, 0, stream>>>(mid, w2T, b2, x2, out,
                                                  M_ROWS, DM, FF);
}

// Round 16
// 270.711 us; speedup vs baseline: 1.0899x; 1.0893x over previous
//
#include <hip/hip_runtime.h>
#include <math.h>

// Transformer block: pre-LN attn + residual, pre-LN MLP(GELU) + residual.
// B=2,S=2048,D=1024,H=16,hd=64,F=4096. fp32 in/out, bf16 MFMA compute.

typedef __attribute__((ext_vector_type(8))) short s8v;    // 8 x bf16 (16B)
typedef __attribute__((ext_vector_type(4))) short s4v;    // 4 x bf16 (8B)
typedef __attribute__((ext_vector_type(4))) float f4v;    // 16x16 MFMA acc
typedef __attribute__((ext_vector_type(16))) float f16v;  // 32x32 MFMA acc

#define M_ROWS 4096
#define DM 1024
#define FF 4096
#define QKV_LD 3072   // fused qkv row stride

__device__ inline short f2bf(float f) {
  unsigned u = __builtin_bit_cast(unsigned, f);
  u += 0x7fff + ((u >> 16) & 1);          // round-to-nearest-even
  return (short)(u >> 16);
}
__device__ inline float bf2f(short s) {
  unsigned u = ((unsigned)(unsigned short)s) << 16;
  return __builtin_bit_cast(float, u);
}

// async global->LDS, 16B per lane. dst wave-uniform base; HW writes
// base + lane*16. src is per-lane.
__device__ inline void gload_lds16(const void* g, void* lds) {
  __builtin_amdgcn_global_load_lds(
      (const __attribute__((address_space(1))) unsigned*)(uintptr_t)g,
      (__attribute__((address_space(3))) unsigned*)(unsigned)(uintptr_t)lds,
      16, 0, 0);
}

// hardware transpose read: lane gathers 4 bf16 (verified rounds 3-14 passing).
__device__ inline s4v ds_tr16(unsigned off) {
  s4v r;
  asm volatile("ds_read_b64_tr_b16 %0, %1" : "=v"(r) : "v"(off));
  return r;
}

__device__ inline s8v cat8(s4v a, s4v b) {
  return __builtin_shufflevector(a, b, 0, 1, 2, 3, 4, 5, 6, 7);
}

// v_cvt_pk_bf16_f32: lo16 = bf16(a), hi16 = bf16(b)  (T12 recipe)
__device__ inline unsigned pkbf(float a, float b) {
  unsigned r;
  asm("v_cvt_pk_bf16_f32 %0, %1, %2" : "=v"(r) : "v"(a), "v"(b));
  return r;
}

// tanh-approx GELU (max err ~3e-3 vs erf-GELU; cheap on VALU) — R9-proven
__device__ inline float gelu_t(float x) {
  float x3 = x * x * x;
  float z = fmaf(x3, 0.044715f, x) * 1.5957691216f;  // 2*0.7978845608
  float e = __expf(z);                               // tanh via sigmoid form
  float th = fmaf(-2.0f, __frcp_rn(e + 1.0f), 1.0f); // 1 - 2/(e^2z+1)
  return 0.5f * x * (1.0f + th);
}

// ---------------- weight transpose+convert: W[K][N] f32 -> Wt[N][K] bf16 ----
__global__ void wt_kernel(const float* __restrict__ W, short* __restrict__ Wt,
                          int K, int N) {
  __shared__ float tile[32][33];
  int tx = threadIdx.x, ty = threadIdx.y;            // (32,8)
  int n0 = blockIdx.x * 32, k0 = blockIdx.y * 32;
#pragma unroll
  for (int i = 0; i < 4; ++i)
    tile[ty + 8 * i][tx] = W[(size_t)(k0 + ty + 8 * i) * N + n0 + tx];
  __syncthreads();
#pragma unroll
  for (int i = 0; i < 4; ++i)
    Wt[(size_t)(n0 + ty + 8 * i) * K + k0 + tx] = f2bf(tile[tx][ty + 8 * i]);
}

// fused 4x 1024x1024 transpose (one launch instead of four)
__global__ void wt4_kernel(const float* __restrict__ w0, const float* __restrict__ w1,
                           const float* __restrict__ w2, const float* __restrict__ w3,
                           short* __restrict__ o0, short* __restrict__ o1,
                           short* __restrict__ o2, short* __restrict__ o3) {
  __shared__ float tile[32][33];
  int tx = threadIdx.x, ty = threadIdx.y;
  int n0 = blockIdx.x * 32, k0 = blockIdx.y * 32;
  int zz = blockIdx.z;
  const float* W = zz == 0 ? w0 : zz == 1 ? w1 : zz == 2 ? w2 : w3;
  short* Wt = zz == 0 ? o0 : zz == 1 ? o1 : zz == 2 ? o2 : o3;
#pragma unroll
  for (int i = 0; i < 4; ++i)
    tile[ty + 8 * i][tx] = W[(size_t)(k0 + ty + 8 * i) * 1024 + n0 + tx];
  __syncthreads();
#pragma unroll
  for (int i = 0; i < 4; ++i)
    Wt[(size_t)(n0 + ty + 8 * i) * 1024 + k0 + tx] = f2bf(tile[tx][ty + 8 * i]);
}

// ---------------- LayerNorm: f32 [rows][1024] -> bf16 ----------------------
__global__ __launch_bounds__(256) void ln_kernel(const float* __restrict__ x,
                                                 const float* __restrict__ g,
                                                 const float* __restrict__ b,
                                                 short* __restrict__ out) {
  int row = blockIdx.x, tid = threadIdx.x;
  const float4* xr = (const float4*)(x + (size_t)row * DM);
  float4 v = xr[tid];                                 // 256 threads * 4 = 1024
  float s = v.x + v.y + v.z + v.w;
  float q = v.x * v.x + v.y * v.y + v.z * v.z + v.w * v.w;
#pragma unroll
  for (int off = 32; off; off >>= 1) {
    s += __shfl_down(s, off);
    q += __shfl_down(q, off);
  }
  __shared__ float red[8];
  if ((tid & 63) == 0) { red[tid >> 6] = s; red[4 + (tid >> 6)] = q; }
  __syncthreads();
  if (tid == 0) {
    float S = red[0] + red[1] + red[2] + red[3];
    float Q = red[4] + red[5] + red[6] + red[7];
    float mean = S * (1.0f / DM);
    float var = Q * (1.0f / DM) - mean * mean;
    red[0] = mean;
    red[1] = rsqrtf(var + 1e-5f);
  }
  __syncthreads();
  float mean = red[0], rstd = red[1];
  float4 gv = ((const float4*)g)[tid], bv = ((const float4*)b)[tid];
  s4v o;
  o[0] = f2bf((v.x - mean) * rstd * gv.x + bv.x);
  o[1] = f2bf((v.y - mean) * rstd * gv.y + bv.y);
  o[2] = f2bf((v.z - mean) * rstd * gv.z + bv.z);
  o[3] = f2bf((v.w - mean) * rstd * gv.w + bv.w);
  *(s4v*)&out[(size_t)row * DM + tid * 4] = o;
}

// ---------------- GEMM 128x128, 2-phase dbuf (R9-proven form) --------------
// EPI 0: C bf16 = acc
// EPI 1: C f32  = acc + bias[n] + res[m,n]
// EPI 2: C bf16 = gelu(acc + bias[n])
template <int EPI>
__global__ __launch_bounds__(256) void gemm_kernel(
    const short* __restrict__ A, const short* __restrict__ Bt,
    const float* __restrict__ bias, const float* __restrict__ res,
    void* __restrict__ Cout, int M, int N, int K) {
  __shared__ short As[2][128 * 64];
  __shared__ short Bs[2][128 * 64];
  int tid = threadIdx.x, lane = tid & 63, wave = tid >> 6;
  int wr = wave >> 1, wc = wave & 1;
  int l16 = lane & 15, lhi = lane >> 4;
  int row0 = blockIdx.y * 128, col0 = blockIdx.x * 128;
  int lrow = lane >> 3, lcol8 = (lane & 7) * 8;     // staging lane coords

  const f4v fzero = {0.f, 0.f, 0.f, 0.f};
  f4v acc[4][4];
#pragma unroll
  for (int m = 0; m < 4; ++m)
#pragma unroll
    for (int n = 0; n < 4; ++n) acc[m][n] = fzero;

  const int nt = K >> 6;

  // prologue: stage tile 0 into buf 0
#pragma unroll
  for (int i = 0; i < 4; ++i) {
    int ch = wave * 4 + i;
    int row = ch * 8 + lrow;
    gload_lds16(&A[(size_t)(row0 + row) * K + lcol8], &As[0][ch * 512]);
    gload_lds16(&Bt[(size_t)(col0 + row) * K + lcol8], &Bs[0][ch * 512]);
  }
  __syncthreads();   // drains vmcnt(0): buf 0 ready

  for (int t = 0; t < nt; ++t) {
    int cur = t & 1, nxt = cur ^ 1;
    if (t + 1 < nt) {
      int k1 = (t + 1) << 6;
#pragma unroll
      for (int i = 0; i < 4; ++i) {
        int ch = wave * 4 + i;
        int row = ch * 8 + lrow;
        gload_lds16(&A[(size_t)(row0 + row) * K + k1 + lcol8], &As[nxt][ch * 512]);
        gload_lds16(&Bt[(size_t)(col0 + row) * K + k1 + lcol8], &Bs[nxt][ch * 512]);
      }
    }
#pragma unroll
    for (int kk = 0; kk < 2; ++kk) {
      s8v af[4], bfr[4];
#pragma unroll
      for (int m = 0; m < 4; ++m)
        af[m] = *(const s8v*)&As[cur][(wr * 64 + m * 16 + l16) * 64 + kk * 32 + lhi * 8];
#pragma unroll
      for (int n = 0; n < 4; ++n)
        bfr[n] = *(const s8v*)&Bs[cur][(wc * 64 + n * 16 + l16) * 64 + kk * 32 + lhi * 8];
#pragma unroll
      for (int m = 0; m < 4; ++m)
#pragma unroll
        for (int n = 0; n < 4; ++n)
          acc[m][n] = __builtin_amdgcn_mfma_f32_16x16x32_bf16(af[m], bfr[n],
                                                              acc[m][n], 0, 0, 0);
    }
    __syncthreads();   // retires prefetch into nxt; releases cur for re-stage
  }

  // epilogue: D layout col=lane&15, row=(lane>>4)*4+reg
#pragma unroll
  for (int m = 0; m < 4; ++m)
#pragma unroll
    for (int n = 0; n < 4; ++n)
#pragma unroll
      for (int r = 0; r < 4; ++r) {
        int row = row0 + wr * 64 + m * 16 + lhi * 4 + r;
        int col = col0 + wc * 64 + n * 16 + l16;
        size_t idx = (size_t)row * N + col;
        float v = acc[m][n][r];
        if (EPI == 0) {
          ((short*)Cout)[idx] = f2bf(v);
        } else if (EPI == 1) {
          ((float*)Cout)[idx] = v + bias[col] + res[idx];
        } else {
          ((short*)Cout)[idx] = f2bf(gelu_t(v + bias[col]));
        }
      }
}

// ---------------- Flash attention, 8-wave blocks, KV-split x2 ---------------
__global__ __launch_bounds__(512) void attn_kernel(const short* __restrict__ q,
                                                   const short* __restrict__ k,
                                                   const short* __restrict__ v,
                                                   short* __restrict__ opart,
                                                   float2* __restrict__ ml) {
  __shared__ short Ks[2][64 * 64];  // [key][d] XOR-swizzled (16B granules)
  __shared__ short Vt[2][64 * 64];  // 4 regions [64 key][16 d] stride-16
  int tid = threadIdx.x, lane = tid & 63, w = tid >> 6;   // w in 0..7
  int l31 = lane & 31, l15 = lane & 15, h = lane >> 5;
  int qb = blockIdx.x * 256;
  int bh = blockIdx.y;
  int sp = blockIdx.z;
  int b = bh >> 4, hh = bh & 15;
  const size_t rbase = (size_t)b * 2048 * QKV_LD + (size_t)hh * 64;
  const float S2 = 0.18033688f;     // 0.125 * log2(e)
  const int kbase = sp * 1024;      // this split's first key

  // staging coords: wave w stages K chunk w (rows w*8..w*8+7) and V chunk w
  int krow = w * 8 + (lane >> 3);
  int kcol = (((lane & 7) ^ (krow & 7)) * 8);
  int vnb = w >> 1, vrem = (w & 1) * 64 + lane;
  int vkey = vrem >> 1, vc8 = vrem & 1;

#define STAGE_KV(buf, kt)                                                      \
  {                                                                            \
    gload_lds16(&k[rbase + (size_t)((kt) + krow) * QKV_LD + kcol],             \
                &Ks[buf][w * 512]);                                            \
    gload_lds16(&v[rbase + (size_t)((kt) + vkey) * QKV_LD + vnb * 16 + vc8 * 8], \
                &Vt[buf][w * 512]);                                            \
  }

  // Q B-fragments: lane holds Q[qrow][16c + 8h .. +8]
  int qrow = qb + w * 32 + l31;
  s8v qf[4];
#pragma unroll
  for (int c = 0; c < 4; ++c)
    qf[c] = *(const s8v*)&q[rbase + (size_t)qrow * QKV_LD + c * 16 + h * 8];

  f16v o0, o1;
#pragma unroll
  for (int i = 0; i < 16; ++i) { o0[i] = 0.f; o1[i] = 0.f; }
  float mreg = -3.0e38f, lsum = 0.f;

  STAGE_KV(0, kbase);
  __syncthreads();   // buf 0 ready

  for (int t = 0; t < 16; ++t) {
    int cur = t & 1;
    if (t + 1 < 16) STAGE_KV(cur ^ 1, kbase + (t + 1) * 64);
    unsigned vtb = (unsigned)(uintptr_t)&Vt[cur][0];

    // ---- T = K @ Q^T (swapped): t0 keys 0..31, t1 keys 32..63
    f16v t0, t1;
#pragma unroll
    for (int i = 0; i < 16; ++i) { t0[i] = 0.f; t1[i] = 0.f; }
    __builtin_amdgcn_s_setprio(1);
#pragma unroll
    for (int c = 0; c < 4; ++c) {
      int slot = ((2 * c + h) ^ (l31 & 7)) * 8;
      s8v k0f = *(const s8v*)&Ks[cur][l31 * 64 + slot];
      s8v k1f = *(const s8v*)&Ks[cur][(32 + l31) * 64 + slot];
      t0 = __builtin_amdgcn_mfma_f32_32x32x16_bf16(k0f, qf[c], t0, 0, 0, 0);
      t1 = __builtin_amdgcn_mfma_f32_32x32x16_bf16(k1f, qf[c], t1, 0, 0, 0);
    }
    __builtin_amdgcn_s_setprio(0);

    // ---- in-register online softmax (raw scores; exp2 with folded scale)
    float mx[8];
#pragma unroll
    for (int i = 0; i < 8; ++i)
      mx[i] = fmaxf(fmaxf(t0[i], t0[i + 8]), fmaxf(t1[i], t1[i + 8]));
    float rm = fmaxf(fmaxf(fmaxf(mx[0], mx[1]), fmaxf(mx[2], mx[3])),
                     fmaxf(fmaxf(mx[4], mx[5]), fmaxf(mx[6], mx[7])));
    rm = fmaxf(rm, __shfl_xor(rm, 32));
    // defer-max (T13): only rescale when some row max grew > 64 raw (8 scaled)
    if (!__all(rm <= mreg + 64.0f)) {
      float newm = fmaxf(mreg, rm);
      float sc = exp2f((mreg - newm) * S2);
      mreg = newm;
#pragma unroll
      for (int i = 0; i < 16; ++i) { o0[i] *= sc; o1[i] *= sc; }
      lsum *= sc;
    }
    float ms2 = mreg * S2;
#pragma unroll
    for (int i = 0; i < 16; ++i) {
      t0[i] = exp2f(fmaf(t0[i], S2, -ms2));
      t1[i] = exp2f(fmaf(t1[i], S2, -ms2));
    }
    float sm[8];
#pragma unroll
    for (int i = 0; i < 8; ++i)
      sm[i] = (t0[i] + t0[i + 8]) + (t1[i] + t1[i + 8]);
    float rs = ((sm[0] + sm[1]) + (sm[2] + sm[3])) +
               ((sm[4] + sm[5]) + (sm[6] + sm[7]));
    rs += __shfl_xor(rs, 32);
    lsum += rs;

    // ---- build PV B-fragments: keys 16c + 8h' + 0..7 per chunk c
    s8v pB[4];
#pragma unroll
    for (int c = 0; c < 4; ++c) {
      int rb = (c & 1) * 8;
      float e0, e1, e2, e3, e4, e5, e6, e7;
      if (c < 2) {
        e0 = t0[rb]; e1 = t0[rb + 1]; e2 = t0[rb + 2]; e3 = t0[rb + 3];
        e4 = t0[rb + 4]; e5 = t0[rb + 5]; e6 = t0[rb + 6]; e7 = t0[rb + 7];
      } else {
        e0 = t1[rb]; e1 = t1[rb + 1]; e2 = t1[rb + 2]; e3 = t1[rb + 3];
        e4 = t1[rb + 4]; e5 = t1[rb + 5]; e6 = t1[rb + 6]; e7 = t1[rb + 7];
      }
      unsigned wA0 = pkbf(e0, e1), wA1 = pkbf(e2, e3);
      unsigned wB0 = pkbf(e4, e5), wB1 = pkbf(e6, e7);
      unsigned s0 = h ? wA0 : wB0, s1 = h ? wA1 : wB1;
      unsigned r0 = __shfl_xor(s0, 32), r1 = __shfl_xor(s1, 32);
      uint4 ww;
      ww.x = h ? r0 : wA0;
      ww.y = h ? r1 : wA1;
      ww.z = h ? wB0 : r0;
      ww.w = h ? wB1 : r1;
      pB[c] = __builtin_bit_cast(s8v, ww);
    }

    // ---- V^T A-fragments via tr reads
    s4v va[2][4][2];
#pragma unroll
    for (int db = 0; db < 2; ++db) {
      unsigned base = vtb + (unsigned)(db * 2 + (l31 >> 4)) * 2048 + 2u * l15;
#pragma unroll
      for (int c = 0; c < 4; ++c) {
        unsigned a = base + (unsigned)(c * 512 + h * 256);  // k0*32 bytes
        va[db][c][0] = ds_tr16(a);
        va[db][c][1] = ds_tr16(a + 128);
      }
    }
    asm volatile("s_waitcnt lgkmcnt(0)");
    __builtin_amdgcn_sched_barrier(0);
    __builtin_amdgcn_s_setprio(1);
#pragma unroll
    for (int c = 0; c < 4; ++c) {
      o0 = __builtin_amdgcn_mfma_f32_32x32x16_bf16(cat8(va[0][c][0], va[0][c][1]),
                                                   pB[c], o0, 0, 0, 0);
      o1 = __builtin_amdgcn_mfma_f32_32x32x16_bf16(cat8(va[1][c][0], va[1][c][1]),
                                                   pB[c], o1, 0, 0, 0);
    }
    __builtin_amdgcn_s_setprio(0);
    __syncthreads();   // retires prefetch; releases cur for next re-stage
  }

  // ---- store UNNORMALIZED partial O (bf16) + (m,l)
  size_t rowg = (size_t)b * 2048 + qrow;
  size_t obase = (size_t)sp * 4096 * 1024 + rowg * 1024 + hh * 64;
#pragma unroll
  for (int db = 0; db < 2; ++db)
#pragma unroll
    for (int qq = 0; qq < 4; ++qq) {
      s4v pv;
#pragma unroll
      for (int i = 0; i < 4; ++i)
        pv[i] = f2bf(db == 0 ? o0[qq * 4 + i] : o1[qq * 4 + i]);
      *(s4v*)&opart[obase + db * 32 + qq * 8 + h * 4] = pv;
    }
  if (h == 0) ml[(size_t)sp * 65536 + rowg * 16 + hh] = make_float2(mreg, lsum);
#undef STAGE_KV
}

// ---------------- combine two KV-split partials -> bf16 attn out -----------
__global__ __launch_bounds__(256) void attn_combine(const short* __restrict__ op,
                                                    const float2* __restrict__ ml,
                                                    short* __restrict__ o) {
  int row = blockIdx.x, t = threadIdx.x;      // 4 outputs per thread
  int head = t >> 4;
  const float S2 = 0.18033688f;
  float2 ml0 = ml[(size_t)row * 16 + head];
  float2 ml1 = ml[65536 + (size_t)row * 16 + head];
  float M = fmaxf(ml0.x, ml1.x);
  float a0 = exp2f((ml0.x - M) * S2);
  float a1 = exp2f((ml1.x - M) * S2);
  float inv = 1.0f / fmaf(ml0.y, a0, ml1.y * a1);
  a0 *= inv; a1 *= inv;
  s4v v0 = *(const s4v*)&op[(size_t)row * 1024 + t * 4];
  s4v v1 = *(const s4v*)&op[(size_t)4096 * 1024 + row * 1024 + t * 4];
  s4v pv;
#pragma unroll
  for (int i = 0; i < 4; ++i)
    pv[i] = f2bf(bf2f(v0[i]) * a0 + bf2f(v1[i]) * a1);
  *(s4v*)&o[(size_t)row * 1024 + t * 4] = pv;
}

// ---------------------------------------------------------------------------
extern "C" void kernel_launch(void* const* d_in, const int* in_sizes, int n_in,
                              void* d_out, int out_size, void* d_ws, size_t ws_size,
                              hipStream_t stream) {
  (void)in_sizes; (void)n_in; (void)out_size; (void)ws_size;
  const float* x    = (const float*)d_in[0];
  const float* ln1g = (const float*)d_in[1];
  const float* ln1b = (const float*)d_in[2];
  const float* wq   = (const float*)d_in[3];
  const float* wk   = (const float*)d_in[4];
  const float* wv   = (const float*)d_in[5];
  const float* wo   = (const float*)d_in[6];
  const float* bo   = (const float*)d_in[7];
  const float* ln2g = (const float*)d_in[8];
  const float* ln2b = (const float*)d_in[9];
  const float* w1   = (const float*)d_in[10];
  const float* b1   = (const float*)d_in[11];
  const float* w2   = (const float*)d_in[12];
  const float* b2   = (const float*)d_in[13];
  float* out = (float*)d_out;

  char* ws = (char*)d_ws;
  const size_t MB = 1024 * 1024;
  short* h1   = (short*)(ws);                 // 8MB  [4096][1024]
  short* qkv  = (short*)(ws + 8 * MB);        // 24MB [4096][3072]
  short* mid  = (short*)(ws);                 // 32MB [4096][4096] (after attn)
  short* at   = (short*)(ws + 32 * MB);       // 8MB  [4096][1024]
  short* h2   = (short*)(ws + 32 * MB);       // reuses at after proj
  float* x2   = (float*)(ws + 40 * MB);       // 16MB f32 residual (after attn)
  short* opart = (short*)(ws + 40 * MB);      // 16MB [2][4096][1024] bf16 partial
  float2* mlb  = (float2*)(ws);               // 1MB  [2][4096][16] (h1 dead)
  short* wqkvT = (short*)(ws + 56 * MB);      // 6MB  [3072][1024]
  short* wqT  = wqkvT;
  short* wkT  = wqkvT + 1024 * 1024;
  short* wvT  = wqkvT + 2 * 1024 * 1024;
  short* woT  = (short*)(ws + 62 * MB);       // 2MB
  short* w1T  = (short*)(ws + 64 * MB);       // 8MB  [4096][1024]
  short* w2T  = (short*)(ws + 72 * MB);       // 8MB  [1024][4096]

  dim3 tb(32, 8);
  wt4_kernel<<<dim3(32, 32, 4), tb, 0, stream>>>(wq, wk, wv, wo,
                                                 wqT, wkT, wvT, woT);
  wt_kernel<<<dim3(128, 32), tb, 0, stream>>>(w1, w1T, 1024, 4096);
  wt_kernel<<<dim3(32, 128), tb, 0, stream>>>(w2, w2T, 4096, 1024);

  ln_kernel<<<M_ROWS, 256, 0, stream>>>(x, ln1g, ln1b, h1);

  // fused QKV: [4096][3072]
  gemm_kernel<0><<<dim3(24, 32), 256, 0, stream>>>(h1, wqkvT, nullptr, nullptr,
                                                   qkv, M_ROWS, QKV_LD, DM);

  attn_kernel<<<dim3(8, 32, 2), 512, 0, stream>>>(qkv, qkv + 1024, qkv + 2048,
                                                  opart, mlb);
  attn_combine<<<4096, 256, 0, stream>>>(opart, mlb, at);

  gemm_kernel<1><<<dim3(8, 32), 256, 0, stream>>>(at, woT, bo, x, x2, M_ROWS, DM, DM);

  ln_kernel<<<M_ROWS, 256, 0, stream>>>(x2, ln2g, ln2b, h2);

  gemm_kernel<2><<<dim3(32, 32), 256, 0, stream>>>(h2, w1T, b1, nullptr, mid,
                                                   M_ROWS, FF, DM);

  gemm_kernel<1><<<dim3(8, 32), 256, 0, stream>>>(mid, w2T, b2, x2, out,
                                                  M_ROWS, DM, FF);
}

// Round 17
// 260.883 us; speedup vs baseline: 1.1309x; 1.0377x over previous
//
#include <hip/hip_runtime.h>
#include <math.h>

// Transformer block: pre-LN attn + residual, pre-LN MLP(GELU) + residual.
// B=2,S=2048,D=1024,H=16,hd=64,F=4096. fp32 in/out, bf16 MFMA compute.

typedef __attribute__((ext_vector_type(8))) short s8v;    // 8 x bf16 (16B)
typedef __attribute__((ext_vector_type(4))) short s4v;    // 4 x bf16 (8B)
typedef __attribute__((ext_vector_type(4))) float f4v;    // 16x16 MFMA acc
typedef __attribute__((ext_vector_type(16))) float f16v;  // 32x32 MFMA acc

#define M_ROWS 4096
#define DM 1024
#define FF 4096
#define QKV_LD 3072   // fused qkv row stride

__device__ inline short f2bf(float f) {
  unsigned u = __builtin_bit_cast(unsigned, f);
  u += 0x7fff + ((u >> 16) & 1);          // round-to-nearest-even
  return (short)(u >> 16);
}
__device__ inline float bf2f(short s) {
  unsigned u = ((unsigned)(unsigned short)s) << 16;
  return __builtin_bit_cast(float, u);
}

// async global->LDS, 16B per lane. dst wave-uniform base; HW writes
// base + lane*16. src is per-lane.
__device__ inline void gload_lds16(const void* g, void* lds) {
  __builtin_amdgcn_global_load_lds(
      (const __attribute__((address_space(1))) unsigned*)(uintptr_t)g,
      (__attribute__((address_space(3))) unsigned*)(unsigned)(uintptr_t)lds,
      16, 0, 0);
}

// hardware transpose read: lane gathers 4 bf16 (verified rounds 3-16 passing).
__device__ inline s4v ds_tr16(unsigned off) {
  s4v r;
  asm volatile("ds_read_b64_tr_b16 %0, %1" : "=v"(r) : "v"(off));
  return r;
}

__device__ inline s8v cat8(s4v a, s4v b) {
  return __builtin_shufflevector(a, b, 0, 1, 2, 3, 4, 5, 6, 7);
}

// v_cvt_pk_bf16_f32: lo16 = bf16(a), hi16 = bf16(b)  (T12 recipe)
__device__ inline unsigned pkbf(float a, float b) {
  unsigned r;
  asm("v_cvt_pk_bf16_f32 %0, %1, %2" : "=v"(r) : "v"(a), "v"(b));
  return r;
}

// tanh-approx GELU (max err ~3e-3 vs erf-GELU; cheap on VALU) — R9-proven
__device__ inline float gelu_t(float x) {
  float x3 = x * x * x;
  float z = fmaf(x3, 0.044715f, x) * 1.5957691216f;  // 2*0.7978845608
  float e = __expf(z);                               // tanh via sigmoid form
  float th = fmaf(-2.0f, __frcp_rn(e + 1.0f), 1.0f); // 1 - 2/(e^2z+1)
  return 0.5f * x * (1.0f + th);
}

// ---------------- weight transpose+convert: W[K][N] f32 -> Wt[N][K] bf16 ----
__global__ void wt_kernel(const float* __restrict__ W, short* __restrict__ Wt,
                          int K, int N) {
  __shared__ float tile[32][33];
  int tx = threadIdx.x, ty = threadIdx.y;            // (32,8)
  int n0 = blockIdx.x * 32, k0 = blockIdx.y * 32;
#pragma unroll
  for (int i = 0; i < 4; ++i)
    tile[ty + 8 * i][tx] = W[(size_t)(k0 + ty + 8 * i) * N + n0 + tx];
  __syncthreads();
#pragma unroll
  for (int i = 0; i < 4; ++i)
    Wt[(size_t)(n0 + ty + 8 * i) * K + k0 + tx] = f2bf(tile[tx][ty + 8 * i]);
}

// fused 4x 1024x1024 transpose (one launch instead of four)
__global__ void wt4_kernel(const float* __restrict__ w0, const float* __restrict__ w1,
                           const float* __restrict__ w2, const float* __restrict__ w3,
                           short* __restrict__ o0, short* __restrict__ o1,
                           short* __restrict__ o2, short* __restrict__ o3) {
  __shared__ float tile[32][33];
  int tx = threadIdx.x, ty = threadIdx.y;
  int n0 = blockIdx.x * 32, k0 = blockIdx.y * 32;
  int zz = blockIdx.z;
  const float* W = zz == 0 ? w0 : zz == 1 ? w1 : zz == 2 ? w2 : w3;
  short* Wt = zz == 0 ? o0 : zz == 1 ? o1 : zz == 2 ? o2 : o3;
#pragma unroll
  for (int i = 0; i < 4; ++i)
    tile[ty + 8 * i][tx] = W[(size_t)(k0 + ty + 8 * i) * 1024 + n0 + tx];
  __syncthreads();
#pragma unroll
  for (int i = 0; i < 4; ++i)
    Wt[(size_t)(n0 + ty + 8 * i) * 1024 + k0 + tx] = f2bf(tile[tx][ty + 8 * i]);
}

// ---------------- LayerNorm: f32 [rows][1024] -> bf16 ----------------------
__global__ __launch_bounds__(256) void ln_kernel(const float* __restrict__ x,
                                                 const float* __restrict__ g,
                                                 const float* __restrict__ b,
                                                 short* __restrict__ out) {
  int row = blockIdx.x, tid = threadIdx.x;
  const float4* xr = (const float4*)(x + (size_t)row * DM);
  float4 v = xr[tid];                                 // 256 threads * 4 = 1024
  float s = v.x + v.y + v.z + v.w;
  float q = v.x * v.x + v.y * v.y + v.z * v.z + v.w * v.w;
#pragma unroll
  for (int off = 32; off; off >>= 1) {
    s += __shfl_down(s, off);
    q += __shfl_down(q, off);
  }
  __shared__ float red[8];
  if ((tid & 63) == 0) { red[tid >> 6] = s; red[4 + (tid >> 6)] = q; }
  __syncthreads();
  if (tid == 0) {
    float S = red[0] + red[1] + red[2] + red[3];
    float Q = red[4] + red[5] + red[6] + red[7];
    float mean = S * (1.0f / DM);
    float var = Q * (1.0f / DM) - mean * mean;
    red[0] = mean;
    red[1] = rsqrtf(var + 1e-5f);
  }
  __syncthreads();
  float mean = red[0], rstd = red[1];
  float4 gv = ((const float4*)g)[tid], bv = ((const float4*)b)[tid];
  s4v o;
  o[0] = f2bf((v.x - mean) * rstd * gv.x + bv.x);
  o[1] = f2bf((v.y - mean) * rstd * gv.y + bv.y);
  o[2] = f2bf((v.z - mean) * rstd * gv.z + bv.z);
  o[3] = f2bf((v.w - mean) * rstd * gv.w + bv.w);
  *(s4v*)&out[(size_t)row * DM + tid * 4] = o;
}

// ---------------- GEMM 128x128, 2-phase dbuf, 32x32x16 MFMA + XOR swizzle --
// Same proven dbuf schedule as R9/R16; inner loop now 16x mfma_32x32x16
// (half the MFMA instructions per K-step). LDS stored with XOR-granule
// swizzle (R11-verified 0-conflict pattern): LDS granule g of row r holds
// source granule g^(r&7); fragment read uses granule (kk*2+h)^(r&7).
// Fragment layouts verified end-to-end by the attn kernel (rounds 4-16):
//   A: row=l&31, k=(l>>5)*8+j   B: col=l&31, k=(l>>5)*8+j
//   C/D: col=l&31, row=(reg&3)+8*(reg>>2)+4*(l>>5)
// EPI 0: C bf16 = acc ; EPI 1: C f32 = acc+bias+res ; EPI 2: C bf16 = gelu
template <int EPI>
__global__ __launch_bounds__(256) void gemm_kernel(
    const short* __restrict__ A, const short* __restrict__ Bt,
    const float* __restrict__ bias, const float* __restrict__ res,
    void* __restrict__ Cout, int M, int N, int K) {
  __shared__ short As[2][128 * 64];
  __shared__ short Bs[2][128 * 64];
  int tid = threadIdx.x, lane = tid & 63, wave = tid >> 6;
  int wr = wave >> 1, wc = wave & 1;
  int l31 = lane & 31, h = lane >> 5;
  int row0 = blockIdx.y * 128, col0 = blockIdx.x * 128;
  int srow = lane >> 3, sg = lane & 7;             // staging lane coords
  int scol = ((sg ^ srow) * 8);                    // pre-swizzled source col

  f16v acc[2][2];
#pragma unroll
  for (int mt = 0; mt < 2; ++mt)
#pragma unroll
    for (int nt = 0; nt < 2; ++nt)
#pragma unroll
      for (int i = 0; i < 16; ++i) acc[mt][nt][i] = 0.f;

  const int nt_loop = K >> 6;

  // prologue: stage tile 0 into buf 0 (swizzled source, linear dest)
#pragma unroll
  for (int i = 0; i < 4; ++i) {
    int ch = wave * 4 + i;
    int row = ch * 8 + srow;
    gload_lds16(&A[(size_t)(row0 + row) * K + scol], &As[0][ch * 512]);
    gload_lds16(&Bt[(size_t)(col0 + row) * K + scol], &Bs[0][ch * 512]);
  }
  __syncthreads();   // drains vmcnt(0): buf 0 ready

  for (int t = 0; t < nt_loop; ++t) {
    int cur = t & 1, nxt = cur ^ 1;
    if (t + 1 < nt_loop) {
      int k1 = (t + 1) << 6;
#pragma unroll
      for (int i = 0; i < 4; ++i) {
        int ch = wave * 4 + i;
        int row = ch * 8 + srow;
        gload_lds16(&A[(size_t)(row0 + row) * K + k1 + scol], &As[nxt][ch * 512]);
        gload_lds16(&Bt[(size_t)(col0 + row) * K + k1 + scol], &Bs[nxt][ch * 512]);
      }
    }
#pragma unroll
    for (int kk = 0; kk < 4; ++kk) {              // 4 x K=16 sub-steps
      s8v af[2], bf[2];
#pragma unroll
      for (int mt = 0; mt < 2; ++mt) {
        int r = wr * 64 + mt * 32 + l31;
        int g = (kk * 2 + h) ^ (r & 7);
        af[mt] = *(const s8v*)&As[cur][r * 64 + g * 8];
      }
#pragma unroll
      for (int ntc = 0; ntc < 2; ++ntc) {
        int r = wc * 64 + ntc * 32 + l31;
        int g = (kk * 2 + h) ^ (r & 7);
        bf[ntc] = *(const s8v*)&Bs[cur][r * 64 + g * 8];
      }
#pragma unroll
      for (int mt = 0; mt < 2; ++mt)
#pragma unroll
        for (int ntc = 0; ntc < 2; ++ntc)
          acc[mt][ntc] = __builtin_amdgcn_mfma_f32_32x32x16_bf16(
              af[mt], bf[ntc], acc[mt][ntc], 0, 0, 0);
    }
    __syncthreads();   // retires prefetch into nxt; releases cur for re-stage
  }

  // epilogue: C/D col=l31, row=(reg&3)+8*(reg>>2)+4*h
#pragma unroll
  for (int mt = 0; mt < 2; ++mt)
#pragma unroll
    for (int ntc = 0; ntc < 2; ++ntc)
#pragma unroll
      for (int reg = 0; reg < 16; ++reg) {
        int rloc = (reg & 3) + 8 * (reg >> 2) + 4 * h;
        int row = row0 + wr * 64 + mt * 32 + rloc;
        int col = col0 + wc * 64 + ntc * 32 + l31;
        size_t idx = (size_t)row * N + col;
        float v = acc[mt][ntc][reg];
        if (EPI == 0) {
          ((short*)Cout)[idx] = f2bf(v);
        } else if (EPI == 1) {
          ((float*)Cout)[idx] = v + bias[col] + res[idx];
        } else {
          ((short*)Cout)[idx] = f2bf(gelu_t(v + bias[col]));
        }
      }
}

// ---------------- Flash attention, 8-wave blocks, KV-split x2 ---------------
__global__ __launch_bounds__(512) void attn_kernel(const short* __restrict__ q,
                                                   const short* __restrict__ k,
                                                   const short* __restrict__ v,
                                                   short* __restrict__ opart,
                                                   float2* __restrict__ ml) {
  __shared__ short Ks[2][64 * 64];  // [key][d] XOR-swizzled (16B granules)
  __shared__ short Vt[2][64 * 64];  // 4 regions [64 key][16 d] stride-16
  int tid = threadIdx.x, lane = tid & 63, w = tid >> 6;   // w in 0..7
  int l31 = lane & 31, l15 = lane & 15, h = lane >> 5;
  int qb = blockIdx.x * 256;
  int bh = blockIdx.y;
  int sp = blockIdx.z;
  int b = bh >> 4, hh = bh & 15;
  const size_t rbase = (size_t)b * 2048 * QKV_LD + (size_t)hh * 64;
  const float S2 = 0.18033688f;     // 0.125 * log2(e)
  const int kbase = sp * 1024;      // this split's first key

  // staging coords: wave w stages K chunk w (rows w*8..w*8+7) and V chunk w
  int krow = w * 8 + (lane >> 3);
  int kcol = (((lane & 7) ^ (krow & 7)) * 8);
  int vnb = w >> 1, vrem = (w & 1) * 64 + lane;
  int vkey = vrem >> 1, vc8 = vrem & 1;

#define STAGE_KV(buf, kt)                                                      \
  {                                                                            \
    gload_lds16(&k[rbase + (size_t)((kt) + krow) * QKV_LD + kcol],             \
                &Ks[buf][w * 512]);                                            \
    gload_lds16(&v[rbase + (size_t)((kt) + vkey) * QKV_LD + vnb * 16 + vc8 * 8], \
                &Vt[buf][w * 512]);                                            \
  }

  // Q B-fragments: lane holds Q[qrow][16c + 8h .. +8]
  int qrow = qb + w * 32 + l31;
  s8v qf[4];
#pragma unroll
  for (int c = 0; c < 4; ++c)
    qf[c] = *(const s8v*)&q[rbase + (size_t)qrow * QKV_LD + c * 16 + h * 8];

  f16v o0, o1;
#pragma unroll
  for (int i = 0; i < 16; ++i) { o0[i] = 0.f; o1[i] = 0.f; }
  float mreg = -3.0e38f, lsum = 0.f;

  STAGE_KV(0, kbase);
  __syncthreads();   // buf 0 ready

  for (int t = 0; t < 16; ++t) {
    int cur = t & 1;
    if (t + 1 < 16) STAGE_KV(cur ^ 1, kbase + (t + 1) * 64);
    unsigned vtb = (unsigned)(uintptr_t)&Vt[cur][0];

    // ---- T = K @ Q^T (swapped): t0 keys 0..31, t1 keys 32..63
    f16v t0, t1;
#pragma unroll
    for (int i = 0; i < 16; ++i) { t0[i] = 0.f; t1[i] = 0.f; }
    __builtin_amdgcn_s_setprio(1);
#pragma unroll
    for (int c = 0; c < 4; ++c) {
      int slot = ((2 * c + h) ^ (l31 & 7)) * 8;
      s8v k0f = *(const s8v*)&Ks[cur][l31 * 64 + slot];
      s8v k1f = *(const s8v*)&Ks[cur][(32 + l31) * 64 + slot];
      t0 = __builtin_amdgcn_mfma_f32_32x32x16_bf16(k0f, qf[c], t0, 0, 0, 0);
      t1 = __builtin_amdgcn_mfma_f32_32x32x16_bf16(k1f, qf[c], t1, 0, 0, 0);
    }
    __builtin_amdgcn_s_setprio(0);

    // ---- in-register online softmax (raw scores; exp2 with folded scale)
    float mx[8];
#pragma unroll
    for (int i = 0; i < 8; ++i)
      mx[i] = fmaxf(fmaxf(t0[i], t0[i + 8]), fmaxf(t1[i], t1[i + 8]));
    float rm = fmaxf(fmaxf(fmaxf(mx[0], mx[1]), fmaxf(mx[2], mx[3])),
                     fmaxf(fmaxf(mx[4], mx[5]), fmaxf(mx[6], mx[7])));
    rm = fmaxf(rm, __shfl_xor(rm, 32));
    // defer-max (T13): only rescale when some row max grew > 64 raw (8 scaled)
    if (!__all(rm <= mreg + 64.0f)) {
      float newm = fmaxf(mreg, rm);
      float sc = exp2f((mreg - newm) * S2);
      mreg = newm;
#pragma unroll
      for (int i = 0; i < 16; ++i) { o0[i] *= sc; o1[i] *= sc; }
      lsum *= sc;
    }
    float ms2 = mreg * S2;
#pragma unroll
    for (int i = 0; i < 16; ++i) {
      t0[i] = exp2f(fmaf(t0[i], S2, -ms2));
      t1[i] = exp2f(fmaf(t1[i], S2, -ms2));
    }
    float sm[8];
#pragma unroll
    for (int i = 0; i < 8; ++i)
      sm[i] = (t0[i] + t0[i + 8]) + (t1[i] + t1[i + 8]);
    float rs = ((sm[0] + sm[1]) + (sm[2] + sm[3])) +
               ((sm[4] + sm[5]) + (sm[6] + sm[7]));
    rs += __shfl_xor(rs, 32);
    lsum += rs;

    // ---- build PV B-fragments: keys 16c + 8h' + 0..7 per chunk c
    s8v pB[4];
#pragma unroll
    for (int c = 0; c < 4; ++c) {
      int rb = (c & 1) * 8;
      float e0, e1, e2, e3, e4, e5, e6, e7;
      if (c < 2) {
        e0 = t0[rb]; e1 = t0[rb + 1]; e2 = t0[rb + 2]; e3 = t0[rb + 3];
        e4 = t0[rb + 4]; e5 = t0[rb + 5]; e6 = t0[rb + 6]; e7 = t0[rb + 7];
      } else {
        e0 = t1[rb]; e1 = t1[rb + 1]; e2 = t1[rb + 2]; e3 = t1[rb + 3];
        e4 = t1[rb + 4]; e5 = t1[rb + 5]; e6 = t1[rb + 6]; e7 = t1[rb + 7];
      }
      unsigned wA0 = pkbf(e0, e1), wA1 = pkbf(e2, e3);
      unsigned wB0 = pkbf(e4, e5), wB1 = pkbf(e6, e7);
      unsigned s0 = h ? wA0 : wB0, s1 = h ? wA1 : wB1;
      unsigned r0 = __shfl_xor(s0, 32), r1 = __shfl_xor(s1, 32);
      uint4 ww;
      ww.x = h ? r0 : wA0;
      ww.y = h ? r1 : wA1;
      ww.z = h ? wB0 : r0;
      ww.w = h ? wB1 : r1;
      pB[c] = __builtin_bit_cast(s8v, ww);
    }

    // ---- V^T A-fragments via tr reads
    s4v va[2][4][2];
#pragma unroll
    for (int db = 0; db < 2; ++db) {
      unsigned base = vtb + (unsigned)(db * 2 + (l31 >> 4)) * 2048 + 2u * l15;
#pragma unroll
      for (int c = 0; c < 4; ++c) {
        unsigned a = base + (unsigned)(c * 512 + h * 256);  // k0*32 bytes
        va[db][c][0] = ds_tr16(a);
        va[db][c][1] = ds_tr16(a + 128);
      }
    }
    asm volatile("s_waitcnt lgkmcnt(0)");
    __builtin_amdgcn_sched_barrier(0);
    __builtin_amdgcn_s_setprio(1);
#pragma unroll
    for (int c = 0; c < 4; ++c) {
      o0 = __builtin_amdgcn_mfma_f32_32x32x16_bf16(cat8(va[0][c][0], va[0][c][1]),
                                                   pB[c], o0, 0, 0, 0);
      o1 = __builtin_amdgcn_mfma_f32_32x32x16_bf16(cat8(va[1][c][0], va[1][c][1]),
                                                   pB[c], o1, 0, 0, 0);
    }
    __builtin_amdgcn_s_setprio(0);
    __syncthreads();   // retires prefetch; releases cur for next re-stage
  }

  // ---- store UNNORMALIZED partial O (bf16) + (m,l)
  size_t rowg = (size_t)b * 2048 + qrow;
  size_t obase = (size_t)sp * 4096 * 1024 + rowg * 1024 + hh * 64;
#pragma unroll
  for (int db = 0; db < 2; ++db)
#pragma unroll
    for (int qq = 0; qq < 4; ++qq) {
      s4v pv;
#pragma unroll
      for (int i = 0; i < 4; ++i)
        pv[i] = f2bf(db == 0 ? o0[qq * 4 + i] : o1[qq * 4 + i]);
      *(s4v*)&opart[obase + db * 32 + qq * 8 + h * 4] = pv;
    }
  if (h == 0) ml[(size_t)sp * 65536 + rowg * 16 + hh] = make_float2(mreg, lsum);
#undef STAGE_KV
}

// ---------------- combine two KV-split partials -> bf16 attn out -----------
__global__ __launch_bounds__(256) void attn_combine(const short* __restrict__ op,
                                                    const float2* __restrict__ ml,
                                                    short* __restrict__ o) {
  int row = blockIdx.x, t = threadIdx.x;      // 4 outputs per thread
  int head = t >> 4;
  const float S2 = 0.18033688f;
  float2 ml0 = ml[(size_t)row * 16 + head];
  float2 ml1 = ml[65536 + (size_t)row * 16 + head];
  float M = fmaxf(ml0.x, ml1.x);
  float a0 = exp2f((ml0.x - M) * S2);
  float a1 = exp2f((ml1.x - M) * S2);
  float inv = 1.0f / fmaf(ml0.y, a0, ml1.y * a1);
  a0 *= inv; a1 *= inv;
  s4v v0 = *(const s4v*)&op[(size_t)row * 1024 + t * 4];
  s4v v1 = *(const s4v*)&op[(size_t)4096 * 1024 + row * 1024 + t * 4];
  s4v pv;
#pragma unroll
  for (int i = 0; i < 4; ++i)
    pv[i] = f2bf(bf2f(v0[i]) * a0 + bf2f(v1[i]) * a1);
  *(s4v*)&o[(size_t)row * 1024 + t * 4] = pv;
}

// ---------------------------------------------------------------------------
extern "C" void kernel_launch(void* const* d_in, const int* in_sizes, int n_in,
                              void* d_out, int out_size, void* d_ws, size_t ws_size,
                              hipStream_t stream) {
  (void)in_sizes; (void)n_in; (void)out_size; (void)ws_size;
  const float* x    = (const float*)d_in[0];
  const float* ln1g = (const float*)d_in[1];
  const float* ln1b = (const float*)d_in[2];
  const float* wq   = (const float*)d_in[3];
  const float* wk   = (const float*)d_in[4];
  const float* wv   = (const float*)d_in[5];
  const float* wo   = (const float*)d_in[6];
  const float* bo   = (const float*)d_in[7];
  const float* ln2g = (const float*)d_in[8];
  const float* ln2b = (const float*)d_in[9];
  const float* w1   = (const float*)d_in[10];
  const float* b1   = (const float*)d_in[11];
  const float* w2   = (const float*)d_in[12];
  const float* b2   = (const float*)d_in[13];
  float* out = (float*)d_out;

  char* ws = (char*)d_ws;
  const size_t MB = 1024 * 1024;
  short* h1   = (short*)(ws);                 // 8MB  [4096][1024]
  short* qkv  = (short*)(ws + 8 * MB);        // 24MB [4096][3072]
  short* mid  = (short*)(ws);                 // 32MB [4096][4096] (after attn)
  short* at   = (short*)(ws + 32 * MB);       // 8MB  [4096][1024]
  short* h2   = (short*)(ws + 32 * MB);       // reuses at after proj
  float* x2   = (float*)(ws + 40 * MB);       // 16MB f32 residual (after attn)
  short* opart = (short*)(ws + 40 * MB);      // 16MB [2][4096][1024] bf16 partial
  float2* mlb  = (float2*)(ws);               // 1MB  [2][4096][16] (h1 dead)
  short* wqkvT = (short*)(ws + 56 * MB);      // 6MB  [3072][1024]
  short* wqT  = wqkvT;
  short* wkT  = wqkvT + 1024 * 1024;
  short* wvT  = wqkvT + 2 * 1024 * 1024;
  short* woT  = (short*)(ws + 62 * MB);       // 2MB
  short* w1T  = (short*)(ws + 64 * MB);       // 8MB  [4096][1024]
  short* w2T  = (short*)(ws + 72 * MB);       // 8MB  [1024][4096]

  dim3 tb(32, 8);
  wt4_kernel<<<dim3(32, 32, 4), tb, 0, stream>>>(wq, wk, wv, wo,
                                                 wqT, wkT, wvT, woT);
  wt_kernel<<<dim3(128, 32), tb, 0, stream>>>(w1, w1T, 1024, 4096);
  wt_kernel<<<dim3(32, 128), tb, 0, stream>>>(w2, w2T, 4096, 1024);

  ln_kernel<<<M_ROWS, 256, 0, stream>>>(x, ln1g, ln1b, h1);

  // fused QKV: [4096][3072]
  gemm_kernel<0><<<dim3(24, 32), 256, 0, stream>>>(h1, wqkvT, nullptr, nullptr,
                                                   qkv, M_ROWS, QKV_LD, DM);

  attn_kernel<<<dim3(8, 32, 2), 512, 0, stream>>>(qkv, qkv + 1024, qkv + 2048,
                                                  opart, mlb);
  attn_combine<<<4096, 256, 0, stream>>>(opart, mlb, at);

  gemm_kernel<1><<<dim3(8, 32), 256, 0, stream>>>(at, woT, bo, x, x2, M_ROWS, DM, DM);

  ln_kernel<<<M_ROWS, 256, 0, stream>>>(x2, ln2g, ln2b, h2);

  gemm_kernel<2><<<dim3(32, 32), 256, 0, stream>>>(h2, w1T, b1, nullptr, mid,
                                                   M_ROWS, FF, DM);

  gemm_kernel<1><<<dim3(8, 32), 256, 0, stream>>>(mid, w2T, b2, x2, out,
                                                  M_ROWS, DM, FF);
}

// Round 18
// 257.618 us; speedup vs baseline: 1.1453x; 1.0127x over previous
//
#include <hip/hip_runtime.h>
#include <math.h>

// Transformer block: pre-LN attn + residual, pre-LN MLP(GELU) + residual.
// B=2,S=2048,D=1024,H=16,hd=64,F=4096. fp32 in/out, bf16 MFMA compute.

typedef __attribute__((ext_vector_type(8))) short s8v;    // 8 x bf16 (16B)
typedef __attribute__((ext_vector_type(4))) short s4v;    // 4 x bf16 (8B)
typedef __attribute__((ext_vector_type(4))) float f4v;    // 16x16 MFMA acc
typedef __attribute__((ext_vector_type(16))) float f16v;  // 32x32 MFMA acc

#define M_ROWS 4096
#define DM 1024
#define FF 4096
#define QKV_LD 3072   // fused qkv row stride

__device__ inline short f2bf(float f) {
  unsigned u = __builtin_bit_cast(unsigned, f);
  u += 0x7fff + ((u >> 16) & 1);          // round-to-nearest-even
  return (short)(u >> 16);
}
__device__ inline float bf2f(short s) {
  unsigned u = ((unsigned)(unsigned short)s) << 16;
  return __builtin_bit_cast(float, u);
}

// async global->LDS, 16B per lane. dst wave-uniform base; HW writes
// base + lane*16. src is per-lane.
__device__ inline void gload_lds16(const void* g, void* lds) {
  __builtin_amdgcn_global_load_lds(
      (const __attribute__((address_space(1))) unsigned*)(uintptr_t)g,
      (__attribute__((address_space(3))) unsigned*)(unsigned)(uintptr_t)lds,
      16, 0, 0);
}

// hardware transpose read: lane gathers 4 bf16 (verified rounds 3-17 passing).
__device__ inline s4v ds_tr16(unsigned off) {
  s4v r;
  asm volatile("ds_read_b64_tr_b16 %0, %1" : "=v"(r) : "v"(off));
  return r;
}

__device__ inline s8v cat8(s4v a, s4v b) {
  return __builtin_shufflevector(a, b, 0, 1, 2, 3, 4, 5, 6, 7);
}

// v_cvt_pk_bf16_f32: lo16 = bf16(a), hi16 = bf16(b)  (T12 recipe)
__device__ inline unsigned pkbf(float a, float b) {
  unsigned r;
  asm("v_cvt_pk_bf16_f32 %0, %1, %2" : "=v"(r) : "v"(a), "v"(b));
  return r;
}

// tanh-approx GELU (max err ~3e-3 vs erf-GELU; cheap on VALU) — R9-proven
__device__ inline float gelu_t(float x) {
  float x3 = x * x * x;
  float z = fmaf(x3, 0.044715f, x) * 1.5957691216f;  // 2*0.7978845608
  float e = __expf(z);                               // tanh via sigmoid form
  float th = fmaf(-2.0f, __frcp_rn(e + 1.0f), 1.0f); // 1 - 2/(e^2z+1)
  return 0.5f * x * (1.0f + th);
}

// ---------------- weight transpose+convert: W[K][N] f32 -> Wt[N][K] bf16 ----
__global__ void wt_kernel(const float* __restrict__ W, short* __restrict__ Wt,
                          int K, int N) {
  __shared__ float tile[32][33];
  int tx = threadIdx.x, ty = threadIdx.y;            // (32,8)
  int n0 = blockIdx.x * 32, k0 = blockIdx.y * 32;
#pragma unroll
  for (int i = 0; i < 4; ++i)
    tile[ty + 8 * i][tx] = W[(size_t)(k0 + ty + 8 * i) * N + n0 + tx];
  __syncthreads();
#pragma unroll
  for (int i = 0; i < 4; ++i)
    Wt[(size_t)(n0 + ty + 8 * i) * K + k0 + tx] = f2bf(tile[tx][ty + 8 * i]);
}

// fused 4x 1024x1024 transpose (one launch instead of four)
__global__ void wt4_kernel(const float* __restrict__ w0, const float* __restrict__ w1,
                           const float* __restrict__ w2, const float* __restrict__ w3,
                           short* __restrict__ o0, short* __restrict__ o1,
                           short* __restrict__ o2, short* __restrict__ o3) {
  __shared__ float tile[32][33];
  int tx = threadIdx.x, ty = threadIdx.y;
  int n0 = blockIdx.x * 32, k0 = blockIdx.y * 32;
  int zz = blockIdx.z;
  const float* W = zz == 0 ? w0 : zz == 1 ? w1 : zz == 2 ? w2 : w3;
  short* Wt = zz == 0 ? o0 : zz == 1 ? o1 : zz == 2 ? o2 : o3;
#pragma unroll
  for (int i = 0; i < 4; ++i)
    tile[ty + 8 * i][tx] = W[(size_t)(k0 + ty + 8 * i) * 1024 + n0 + tx];
  __syncthreads();
#pragma unroll
  for (int i = 0; i < 4; ++i)
    Wt[(size_t)(n0 + ty + 8 * i) * 1024 + k0 + tx] = f2bf(tile[tx][ty + 8 * i]);
}

// ---------------- LayerNorm: f32 [rows][1024] -> bf16 ----------------------
__global__ __launch_bounds__(256) void ln_kernel(const float* __restrict__ x,
                                                 const float* __restrict__ g,
                                                 const float* __restrict__ b,
                                                 short* __restrict__ out) {
  int row = blockIdx.x, tid = threadIdx.x;
  const float4* xr = (const float4*)(x + (size_t)row * DM);
  float4 v = xr[tid];                                 // 256 threads * 4 = 1024
  float s = v.x + v.y + v.z + v.w;
  float q = v.x * v.x + v.y * v.y + v.z * v.z + v.w * v.w;
#pragma unroll
  for (int off = 32; off; off >>= 1) {
    s += __shfl_down(s, off);
    q += __shfl_down(q, off);
  }
  __shared__ float red[8];
  if ((tid & 63) == 0) { red[tid >> 6] = s; red[4 + (tid >> 6)] = q; }
  __syncthreads();
  if (tid == 0) {
    float S = red[0] + red[1] + red[2] + red[3];
    float Q = red[4] + red[5] + red[6] + red[7];
    float mean = S * (1.0f / DM);
    float var = Q * (1.0f / DM) - mean * mean;
    red[0] = mean;
    red[1] = rsqrtf(var + 1e-5f);
  }
  __syncthreads();
  float mean = red[0], rstd = red[1];
  float4 gv = ((const float4*)g)[tid], bv = ((const float4*)b)[tid];
  s4v o;
  o[0] = f2bf((v.x - mean) * rstd * gv.x + bv.x);
  o[1] = f2bf((v.y - mean) * rstd * gv.y + bv.y);
  o[2] = f2bf((v.z - mean) * rstd * gv.z + bv.z);
  o[3] = f2bf((v.w - mean) * rstd * gv.w + bv.w);
  *(s4v*)&out[(size_t)row * DM + tid * 4] = o;
}

// ---------------- GEMM 128x128, 2-phase dbuf, 32x32x16 MFMA + XOR swizzle --
// (R17-proven). EPI 0: bf16 = acc; 1: f32 = acc+bias+res; 2: bf16 = gelu.
template <int EPI>
__global__ __launch_bounds__(256) void gemm_kernel(
    const short* __restrict__ A, const short* __restrict__ Bt,
    const float* __restrict__ bias, const float* __restrict__ res,
    void* __restrict__ Cout, int M, int N, int K) {
  __shared__ short As[2][128 * 64];
  __shared__ short Bs[2][128 * 64];
  int tid = threadIdx.x, lane = tid & 63, wave = tid >> 6;
  int wr = wave >> 1, wc = wave & 1;
  int l31 = lane & 31, h = lane >> 5;
  int row0 = blockIdx.y * 128, col0 = blockIdx.x * 128;
  int srow = lane >> 3, sg = lane & 7;             // staging lane coords
  int scol = ((sg ^ srow) * 8);                    // pre-swizzled source col

  f16v acc[2][2];
#pragma unroll
  for (int mt = 0; mt < 2; ++mt)
#pragma unroll
    for (int nt = 0; nt < 2; ++nt)
#pragma unroll
      for (int i = 0; i < 16; ++i) acc[mt][nt][i] = 0.f;

  const int nt_loop = K >> 6;

  // prologue: stage tile 0 into buf 0 (swizzled source, linear dest)
#pragma unroll
  for (int i = 0; i < 4; ++i) {
    int ch = wave * 4 + i;
    int row = ch * 8 + srow;
    gload_lds16(&A[(size_t)(row0 + row) * K + scol], &As[0][ch * 512]);
    gload_lds16(&Bt[(size_t)(col0 + row) * K + scol], &Bs[0][ch * 512]);
  }
  __syncthreads();   // drains vmcnt(0): buf 0 ready

  for (int t = 0; t < nt_loop; ++t) {
    int cur = t & 1, nxt = cur ^ 1;
    if (t + 1 < nt_loop) {
      int k1 = (t + 1) << 6;
#pragma unroll
      for (int i = 0; i < 4; ++i) {
        int ch = wave * 4 + i;
        int row = ch * 8 + srow;
        gload_lds16(&A[(size_t)(row0 + row) * K + k1 + scol], &As[nxt][ch * 512]);
        gload_lds16(&Bt[(size_t)(col0 + row) * K + k1 + scol], &Bs[nxt][ch * 512]);
      }
    }
#pragma unroll
    for (int kk = 0; kk < 4; ++kk) {              // 4 x K=16 sub-steps
      s8v af[2], bf[2];
#pragma unroll
      for (int mt = 0; mt < 2; ++mt) {
        int r = wr * 64 + mt * 32 + l31;
        int g = (kk * 2 + h) ^ (r & 7);
        af[mt] = *(const s8v*)&As[cur][r * 64 + g * 8];
      }
#pragma unroll
      for (int ntc = 0; ntc < 2; ++ntc) {
        int r = wc * 64 + ntc * 32 + l31;
        int g = (kk * 2 + h) ^ (r & 7);
        bf[ntc] = *(const s8v*)&Bs[cur][r * 64 + g * 8];
      }
#pragma unroll
      for (int mt = 0; mt < 2; ++mt)
#pragma unroll
        for (int ntc = 0; ntc < 2; ++ntc)
          acc[mt][ntc] = __builtin_amdgcn_mfma_f32_32x32x16_bf16(
              af[mt], bf[ntc], acc[mt][ntc], 0, 0, 0);
    }
    __syncthreads();   // retires prefetch into nxt; releases cur for re-stage
  }

  // epilogue: C/D col=l31, row=(reg&3)+8*(reg>>2)+4*h
#pragma unroll
  for (int mt = 0; mt < 2; ++mt)
#pragma unroll
    for (int ntc = 0; ntc < 2; ++ntc)
#pragma unroll
      for (int reg = 0; reg < 16; ++reg) {
        int rloc = (reg & 3) + 8 * (reg >> 2) + 4 * h;
        int row = row0 + wr * 64 + mt * 32 + rloc;
        int col = col0 + wc * 64 + ntc * 32 + l31;
        size_t idx = (size_t)row * N + col;
        float v = acc[mt][ntc][reg];
        if (EPI == 0) {
          ((short*)Cout)[idx] = f2bf(v);
        } else if (EPI == 1) {
          ((float*)Cout)[idx] = v + bias[col] + res[idx];
        } else {
          ((short*)Cout)[idx] = f2bf(gelu_t(v + bias[col]));
        }
      }
}

// ---------------- Flash attention, 8-wave blocks, KV-split x2 ---------------
__global__ __launch_bounds__(512) void attn_kernel(const short* __restrict__ q,
                                                   const short* __restrict__ k,
                                                   const short* __restrict__ v,
                                                   short* __restrict__ opart,
                                                   float2* __restrict__ ml) {
  __shared__ short Ks[2][64 * 64];  // [key][d] XOR-swizzled (16B granules)
  __shared__ short Vt[2][64 * 64];  // 4 regions [64 key][16 d] stride-16
  int tid = threadIdx.x, lane = tid & 63, w = tid >> 6;   // w in 0..7
  int l31 = lane & 31, l15 = lane & 15, h = lane >> 5;
  int qb = blockIdx.x * 256;
  int bh = blockIdx.y;
  int sp = blockIdx.z;
  int b = bh >> 4, hh = bh & 15;
  const size_t rbase = (size_t)b * 2048 * QKV_LD + (size_t)hh * 64;
  const float S2 = 0.18033688f;     // 0.125 * log2(e)
  const int kbase = sp * 1024;      // this split's first key

  // staging coords: wave w stages K chunk w (rows w*8..w*8+7) and V chunk w
  int krow = w * 8 + (lane >> 3);
  int kcol = (((lane & 7) ^ (krow & 7)) * 8);
  int vnb = w >> 1, vrem = (w & 1) * 64 + lane;
  int vkey = vrem >> 1, vc8 = vrem & 1;

#define STAGE_KV(buf, kt)                                                      \
  {                                                                            \
    gload_lds16(&k[rbase + (size_t)((kt) + krow) * QKV_LD + kcol],             \
                &Ks[buf][w * 512]);                                            \
    gload_lds16(&v[rbase + (size_t)((kt) + vkey) * QKV_LD + vnb * 16 + vc8 * 8], \
                &Vt[buf][w * 512]);                                            \
  }

  // Q B-fragments: lane holds Q[qrow][16c + 8h .. +8]
  int qrow = qb + w * 32 + l31;
  s8v qf[4];
#pragma unroll
  for (int c = 0; c < 4; ++c)
    qf[c] = *(const s8v*)&q[rbase + (size_t)qrow * QKV_LD + c * 16 + h * 8];

  f16v o0, o1;
#pragma unroll
  for (int i = 0; i < 16; ++i) { o0[i] = 0.f; o1[i] = 0.f; }
  float mreg = -3.0e38f, lsum = 0.f;

  STAGE_KV(0, kbase);
  __syncthreads();   // buf 0 ready

  for (int t = 0; t < 16; ++t) {
    int cur = t & 1;
    if (t + 1 < 16) STAGE_KV(cur ^ 1, kbase + (t + 1) * 64);
    unsigned vtb = (unsigned)(uintptr_t)&Vt[cur][0];

    // ---- T = K @ Q^T (swapped): t0 keys 0..31, t1 keys 32..63
    f16v t0, t1;
#pragma unroll
    for (int i = 0; i < 16; ++i) { t0[i] = 0.f; t1[i] = 0.f; }
    __builtin_amdgcn_s_setprio(1);
#pragma unroll
    for (int c = 0; c < 4; ++c) {
      int slot = ((2 * c + h) ^ (l31 & 7)) * 8;
      s8v k0f = *(const s8v*)&Ks[cur][l31 * 64 + slot];
      s8v k1f = *(const s8v*)&Ks[cur][(32 + l31) * 64 + slot];
      t0 = __builtin_amdgcn_mfma_f32_32x32x16_bf16(k0f, qf[c], t0, 0, 0, 0);
      t1 = __builtin_amdgcn_mfma_f32_32x32x16_bf16(k1f, qf[c], t1, 0, 0, 0);
    }
    __builtin_amdgcn_s_setprio(0);

    // ---- in-register online softmax (raw scores; exp2 with folded scale)
    float mx[8];
#pragma unroll
    for (int i = 0; i < 8; ++i)
      mx[i] = fmaxf(fmaxf(t0[i], t0[i + 8]), fmaxf(t1[i], t1[i + 8]));
    float rm = fmaxf(fmaxf(fmaxf(mx[0], mx[1]), fmaxf(mx[2], mx[3])),
                     fmaxf(fmaxf(mx[4], mx[5]), fmaxf(mx[6], mx[7])));
    rm = fmaxf(rm, __shfl_xor(rm, 32));
    // defer-max (T13): only rescale when some row max grew > 64 raw (8 scaled)
    if (!__all(rm <= mreg + 64.0f)) {
      float newm = fmaxf(mreg, rm);
      float sc = exp2f((mreg - newm) * S2);
      mreg = newm;
#pragma unroll
      for (int i = 0; i < 16; ++i) { o0[i] *= sc; o1[i] *= sc; }
      lsum *= sc;
    }
    float ms2 = mreg * S2;
#pragma unroll
    for (int i = 0; i < 16; ++i) {
      t0[i] = exp2f(fmaf(t0[i], S2, -ms2));
      t1[i] = exp2f(fmaf(t1[i], S2, -ms2));
    }
    float sm[8];
#pragma unroll
    for (int i = 0; i < 8; ++i)
      sm[i] = (t0[i] + t0[i + 8]) + (t1[i] + t1[i + 8]);
    float rs = ((sm[0] + sm[1]) + (sm[2] + sm[3])) +
               ((sm[4] + sm[5]) + (sm[6] + sm[7]));
    rs += __shfl_xor(rs, 32);
    lsum += rs;

    // ---- build PV B-fragments via v_permlane32_swap_b32 (T12):
    // per chunk: 4 cvt_pk + 2 permlane (replaces 2 bpermute + 8 selects).
    // swap(wB, wA): wB[i<32]<-wA[i+32], wA[i>=32]<-wB[i-32] => ww ordering
    // reproduced bit-exactly for both halves.
    s8v pB[4];
#pragma unroll
    for (int c = 0; c < 4; ++c) {
      int rb = (c & 1) * 8;
      float e0, e1, e2, e3, e4, e5, e6, e7;
      if (c < 2) {
        e0 = t0[rb]; e1 = t0[rb + 1]; e2 = t0[rb + 2]; e3 = t0[rb + 3];
        e4 = t0[rb + 4]; e5 = t0[rb + 5]; e6 = t0[rb + 6]; e7 = t0[rb + 7];
      } else {
        e0 = t1[rb]; e1 = t1[rb + 1]; e2 = t1[rb + 2]; e3 = t1[rb + 3];
        e4 = t1[rb + 4]; e5 = t1[rb + 5]; e6 = t1[rb + 6]; e7 = t1[rb + 7];
      }
      unsigned wA0 = pkbf(e0, e1), wA1 = pkbf(e2, e3);
      unsigned wB0 = pkbf(e4, e5), wB1 = pkbf(e6, e7);
      asm volatile("v_permlane32_swap_b32 %0, %1" : "+v"(wB0), "+v"(wA0));
      asm volatile("v_permlane32_swap_b32 %0, %1" : "+v"(wB1), "+v"(wA1));
      uint4 ww;
      ww.x = wA0;
      ww.y = wA1;
      ww.z = wB0;
      ww.w = wB1;
      pB[c] = __builtin_bit_cast(s8v, ww);
    }

    // ---- V^T A-fragments via tr reads
    s4v va[2][4][2];
#pragma unroll
    for (int db = 0; db < 2; ++db) {
      unsigned base = vtb + (unsigned)(db * 2 + (l31 >> 4)) * 2048 + 2u * l15;
#pragma unroll
      for (int c = 0; c < 4; ++c) {
        unsigned a = base + (unsigned)(c * 512 + h * 256);  // k0*32 bytes
        va[db][c][0] = ds_tr16(a);
        va[db][c][1] = ds_tr16(a + 128);
      }
    }
    asm volatile("s_waitcnt lgkmcnt(0)");
    __builtin_amdgcn_sched_barrier(0);
    __builtin_amdgcn_s_setprio(1);
#pragma unroll
    for (int c = 0; c < 4; ++c) {
      o0 = __builtin_amdgcn_mfma_f32_32x32x16_bf16(cat8(va[0][c][0], va[0][c][1]),
                                                   pB[c], o0, 0, 0, 0);
      o1 = __builtin_amdgcn_mfma_f32_32x32x16_bf16(cat8(va[1][c][0], va[1][c][1]),
                                                   pB[c], o1, 0, 0, 0);
    }
    __builtin_amdgcn_s_setprio(0);
    __syncthreads();   // retires prefetch; releases cur for next re-stage
  }

  // ---- store UNNORMALIZED partial O (bf16) + (m,l)
  size_t rowg = (size_t)b * 2048 + qrow;
  size_t obase = (size_t)sp * 4096 * 1024 + rowg * 1024 + hh * 64;
#pragma unroll
  for (int db = 0; db < 2; ++db)
#pragma unroll
    for (int qq = 0; qq < 4; ++qq) {
      s4v pv;
#pragma unroll
      for (int i = 0; i < 4; ++i)
        pv[i] = f2bf(db == 0 ? o0[qq * 4 + i] : o1[qq * 4 + i]);
      *(s4v*)&opart[obase + db * 32 + qq * 8 + h * 4] = pv;
    }
  if (h == 0) ml[(size_t)sp * 65536 + rowg * 16 + hh] = make_float2(mreg, lsum);
#undef STAGE_KV
}

// ---------------- combine two KV-split partials -> bf16 attn out -----------
__global__ __launch_bounds__(256) void attn_combine(const short* __restrict__ op,
                                                    const float2* __restrict__ ml,
                                                    short* __restrict__ o) {
  int row = blockIdx.x, t = threadIdx.x;      // 4 outputs per thread
  int head = t >> 4;
  const float S2 = 0.18033688f;
  float2 ml0 = ml[(size_t)row * 16 + head];
  float2 ml1 = ml[65536 + (size_t)row * 16 + head];
  float M = fmaxf(ml0.x, ml1.x);
  float a0 = exp2f((ml0.x - M) * S2);
  float a1 = exp2f((ml1.x - M) * S2);
  float inv = 1.0f / fmaf(ml0.y, a0, ml1.y * a1);
  a0 *= inv; a1 *= inv;
  s4v v0 = *(const s4v*)&op[(size_t)row * 1024 + t * 4];
  s4v v1 = *(const s4v*)&op[(size_t)4096 * 1024 + row * 1024 + t * 4];
  s4v pv;
#pragma unroll
  for (int i = 0; i < 4; ++i)
    pv[i] = f2bf(bf2f(v0[i]) * a0 + bf2f(v1[i]) * a1);
  *(s4v*)&o[(size_t)row * 1024 + t * 4] = pv;
}

// ---------------------------------------------------------------------------
extern "C" void kernel_launch(void* const* d_in, const int* in_sizes, int n_in,
                              void* d_out, int out_size, void* d_ws, size_t ws_size,
                              hipStream_t stream) {
  (void)in_sizes; (void)n_in; (void)out_size; (void)ws_size;
  const float* x    = (const float*)d_in[0];
  const float* ln1g = (const float*)d_in[1];
  const float* ln1b = (const float*)d_in[2];
  const float* wq   = (const float*)d_in[3];
  const float* wk   = (const float*)d_in[4];
  const float* wv   = (const float*)d_in[5];
  const float* wo   = (const float*)d_in[6];
  const float* bo   = (const float*)d_in[7];
  const float* ln2g = (const float*)d_in[8];
  const float* ln2b = (const float*)d_in[9];
  const float* w1   = (const float*)d_in[10];
  const float* b1   = (const float*)d_in[11];
  const float* w2   = (const float*)d_in[12];
  const float* b2   = (const float*)d_in[13];
  float* out = (float*)d_out;

  char* ws = (char*)d_ws;
  const size_t MB = 1024 * 1024;
  short* h1   = (short*)(ws);                 // 8MB  [4096][1024]
  short* qkv  = (short*)(ws + 8 * MB);        // 24MB [4096][3072]
  short* mid  = (short*)(ws);                 // 32MB [4096][4096] (after attn)
  short* at   = (short*)(ws + 32 * MB);       // 8MB  [4096][1024]
  short* h2   = (short*)(ws + 32 * MB);       // reuses at after proj
  float* x2   = (float*)(ws + 40 * MB);       // 16MB f32 residual (after attn)
  short* opart = (short*)(ws + 40 * MB);      // 16MB [2][4096][1024] bf16 partial
  float2* mlb  = (float2*)(ws);               // 1MB  [2][4096][16] (h1 dead)
  short* wqkvT = (short*)(ws + 56 * MB);      // 6MB  [3072][1024]
  short* wqT  = wqkvT;
  short* wkT  = wqkvT + 1024 * 1024;
  short* wvT  = wqkvT + 2 * 1024 * 1024;
  short* woT  = (short*)(ws + 62 * MB);       // 2MB
  short* w1T  = (short*)(ws + 64 * MB);       // 8MB  [4096][1024]
  short* w2T  = (short*)(ws + 72 * MB);       // 8MB  [1024][4096]

  dim3 tb(32, 8);
  wt4_kernel<<<dim3(32, 32, 4), tb, 0, stream>>>(wq, wk, wv, wo,
                                                 wqT, wkT, wvT, woT);
  wt_kernel<<<dim3(128, 32), tb, 0, stream>>>(w1, w1T, 1024, 4096);
  wt_kernel<<<dim3(32, 128), tb, 0, stream>>>(w2, w2T, 4096, 1024);

  ln_kernel<<<M_ROWS, 256, 0, stream>>>(x, ln1g, ln1b, h1);

  // fused QKV: [4096][3072]
  gemm_kernel<0><<<dim3(24, 32), 256, 0, stream>>>(h1, wqkvT, nullptr, nullptr,
                                                   qkv, M_ROWS, QKV_LD, DM);

  attn_kernel<<<dim3(8, 32, 2), 512, 0, stream>>>(qkv, qkv + 1024, qkv + 2048,
                                                  opart, mlb);
  attn_combine<<<4096, 256, 0, stream>>>(opart, mlb, at);

  gemm_kernel<1><<<dim3(8, 32), 256, 0, stream>>>(at, woT, bo, x, x2, M_ROWS, DM, DM);

  ln_kernel<<<M_ROWS, 256, 0, stream>>>(x2, ln2g, ln2b, h2);

  gemm_kernel<2><<<dim3(32, 32), 256, 0, stream>>>(h2, w1T, b1, nullptr, mid,
                                                   M_ROWS, FF, DM);

  gemm_kernel<1><<<dim3(8, 32), 256, 0, stream>>>(mid, w2T, b2, x2, out,
                                                  M_ROWS, DM, FF);
}